// Round 1
// baseline (189.433 us; speedup 1.0000x reference)
//
#include <hip/hip_runtime.h>

// ---- problem constants (fixed by the reference) ----
#define BATCH   32
#define L1N     8192
#define L2N     32768
#define LTOT    40960
#define CD      32       // CONV_DEPTH
#define SPK     8        // S = 2^3
#define O1      256      // EMBED_DIM
#define L1P     1024     // L1N / S
#define L2P     4096     // L2N / S

__device__ __forceinline__ float4 f4add(float4 a, float4 b) {
    return make_float4(a.x + b.x, a.y + b.y, a.z + b.z, a.w + b.w);
}

// ---------------------------------------------------------------------------
// Pre-pass: transpose conv weights to [k][o] layout, k = c*8+s (natural flat
// index of (C,S)), so w1p[k*256+o] = conv1_w[o*256+k].
// ---------------------------------------------------------------------------
__global__ void k_pre(const float* __restrict__ w1, const float* __restrict__ w2,
                      float* __restrict__ w1p, float* __restrict__ w2p) {
    int i = blockIdx.x * 256 + threadIdx.x;      // 65536 threads
    if (i < 256 * 256) {
        int k = i >> 8, o = i & 255;
        w1p[i] = w1[o * 256 + k];
    }
    if (i < 256 * 32) {
        int k = i >> 5, o = i & 31;
        w2p[i] = w2[o * 256 + k];
    }
}

// ---------------------------------------------------------------------------
// Per-batch-row prefix sums: order1 (substitution gather index, -1 if not
// masked) over L1N, dst2 (compaction destination, -1 if dropped) over L2P.
// One block per batch row.
// ---------------------------------------------------------------------------
__global__ void k_scan(const int* __restrict__ value,
                       int* __restrict__ order1, int* __restrict__ dst2) {
    int b = blockIdx.x, tid = threadIdx.x;
    __shared__ int part[256];

    // ---- phase 1: mask = (val1 == 2) over 8192, 32 elems/thread ----
    const int* v1 = value + b * LTOT;
    int base = tid * 32;
    int cnt = 0;
    for (int i = 0; i < 32; ++i) cnt += (v1[base + i] == 2);
    part[tid] = cnt;
    __syncthreads();
    for (int off = 1; off < 256; off <<= 1) {
        int t = (tid >= off) ? part[tid - off] : 0;
        __syncthreads();
        part[tid] += t;
        __syncthreads();
    }
    int run = part[tid] - cnt;  // exclusive prefix
    for (int i = 0; i < 32; ++i) {
        int l = base + i;
        bool m = (v1[l] == 2);
        int ord = run < (L2P - 1) ? run : (L2P - 1);
        order1[b * L1N + l] = m ? ord : -1;
        run += m ? 1 : 0;
    }
    __syncthreads();

    // ---- phase 2: sel = (val2[::8] != 0) over 4096, 16 elems/thread ----
    const int* v2 = value + b * LTOT + L1N;
    int base2 = tid * 16;
    int cnt2 = 0;
    for (int i = 0; i < 16; ++i) cnt2 += (v2[(base2 + i) * 8] != 0);
    part[tid] = cnt2;
    __syncthreads();
    for (int off = 1; off < 256; off <<= 1) {
        int t = (tid >= off) ? part[tid - off] : 0;
        __syncthreads();
        part[tid] += t;
        __syncthreads();
    }
    int run2 = part[tid] - cnt2;
    for (int i = 0; i < 16; ++i) {
        int j = base2 + i;
        bool s = (v2[j * 8] != 0);
        dst2[b * L2P + j] = s ? run2 : -1;
        run2 += s ? 1 : 0;
    }
}

// ---------------------------------------------------------------------------
// conv2: embed2 on the fly -> GEMM (M=131072, K=256, N=32) -> scatter to y_c.
// Block: 128 M-rows x 32 O.  256 threads, 4x4 per-thread tile (32x8 grid).
// K chunked by 32 (c-chunk of 4, all s).
// ---------------------------------------------------------------------------
__global__ __launch_bounds__(256) void k_conv2(
    const int* __restrict__ value, const int* __restrict__ depth,
    const int* __restrict__ pos,
    const float* __restrict__ ve2, const float* __restrict__ de2,
    const float* __restrict__ se2,
    const float* __restrict__ w2p, const float* __restrict__ b2,
    const int* __restrict__ dst2, float* __restrict__ y_c) {
    int tid = threadIdx.x;
    int tile = blockIdx.x;  // 1024 tiles of 128 rows
    __shared__ float Al[32][132];
    __shared__ float Bl[32][36];
    float acc[4][4] = {};
    int g0 = tile * 128;

    for (int ch = 0; ch < 8; ++ch) {
        int c0 = ch * 4;
        // stage A: 1024 tokens (128 m x 8 s) x 4 c
        for (int tt = 0; tt < 4; ++tt) {
            int t = tt * 256 + tid;       // 0..1023
            int m = t >> 3, s = t & 7;
            int g = g0 + m;
            int b = g >> 12, l2 = g & (L2P - 1);
            int tok = b * LTOT + L1N + l2 * 8 + s;
            int val = value[tok];
            int dep = depth[tok];
            const int* pp = pos + (size_t)tok * 3;
            int p0 = pp[0], p1 = pp[1], p2 = pp[2];
            float4 e = *(const float4*)(ve2 + val * CD + c0);
            e = f4add(e, *(const float4*)(de2 + dep * CD + c0));
            e = f4add(e, *(const float4*)(se2 + (p0) * CD + c0));
            e = f4add(e, *(const float4*)(se2 + (128 + p1) * CD + c0));
            e = f4add(e, *(const float4*)(se2 + (256 + p2) * CD + c0));
            Al[s][m] = e.x;
            Al[8 + s][m] = e.y;
            Al[16 + s][m] = e.z;
            Al[24 + s][m] = e.w;
        }
        // stage B: 32 k x 32 o
        for (int j = 0; j < 4; ++j) {
            int i = j * 256 + tid;
            int kl = i >> 5, o = i & 31;
            Bl[kl][o] = w2p[(ch * 32 + kl) * 32 + o];
        }
        __syncthreads();
        int mo = (tid >> 3) * 4, oo = (tid & 7) * 4;
        #pragma unroll
        for (int kk = 0; kk < 32; ++kk) {
            float av[4], bv[4];
            *(float4*)av = *(const float4*)&Al[kk][mo];
            *(float4*)bv = *(const float4*)&Bl[kk][oo];
            #pragma unroll
            for (int i = 0; i < 4; ++i)
                #pragma unroll
                for (int j = 0; j < 4; ++j) acc[i][j] += av[i] * bv[j];
        }
        __syncthreads();
    }

    // epilogue: add bias, scatter-compact
    int mo = (tid >> 3) * 4, oo = (tid & 7) * 4;
    float4 bias = *(const float4*)(b2 + oo);
    for (int i = 0; i < 4; ++i) {
        int g = g0 + mo + i;
        int b = g >> 12, l2 = g & (L2P - 1);
        int d = dst2[b * L2P + l2];
        if (d >= 0) {
            float4 r = make_float4(acc[i][0] + bias.x, acc[i][1] + bias.y,
                                   acc[i][2] + bias.z, acc[i][3] + bias.w);
            *(float4*)(y_c + ((size_t)(b * L2P + d)) * CD + oo) = r;
        }
    }
}

// ---------------------------------------------------------------------------
// conv1: embed1 + substitution gather -> GEMM (M=32768, K=256, N=256).
// Block: 64 M-rows x 64 O.  256 threads, 4x4 per-thread tile (16x16 grid).
// K chunked by 64 (c-chunk of 8, all s).
// ---------------------------------------------------------------------------
__global__ __launch_bounds__(256) void k_conv1(
    const int* __restrict__ value, const int* __restrict__ depth,
    const int* __restrict__ pos,
    const float* __restrict__ ve1, const float* __restrict__ de1,
    const float* __restrict__ se1,
    const float* __restrict__ w1p, const float* __restrict__ b1,
    const int* __restrict__ order1, const float* __restrict__ y_c,
    float* __restrict__ out) {
    int tid = threadIdx.x;
    int tm = blockIdx.x;  // 512 tiles of 64 rows
    int tn = blockIdx.y;  // 4 tiles of 64 o
    __shared__ float Al[64][68];
    __shared__ float Bl[64][68];
    float acc[4][4] = {};
    int g0 = tm * 64;

    for (int ch = 0; ch < 4; ++ch) {
        int c0 = ch * 8;
        // stage A: 512 tokens (64 m x 8 s) x 8 c
        for (int tt = 0; tt < 2; ++tt) {
            int t = tt * 256 + tid;   // 0..511
            int m = t >> 3, s = t & 7;
            int g = g0 + m;
            int b = g >> 10, l = g & (L1P - 1);
            int tokl = l * 8 + s;
            int tok = b * LTOT + tokl;
            int val = value[tok];
            float4 e0, e1;
            if (val == 2) {
                int ord = order1[b * L1N + tokl];
                const float* src = y_c + ((size_t)(b * L2P + ord)) * CD + c0;
                e0 = *(const float4*)(src);
                e1 = *(const float4*)(src + 4);
            } else {
                int dep = depth[tok];
                const int* pp = pos + (size_t)tok * 3;
                int p0 = pp[0], p1 = pp[1], p2 = pp[2];
                e0 = *(const float4*)(ve1 + val * CD + c0);
                e1 = *(const float4*)(ve1 + val * CD + c0 + 4);
                e0 = f4add(e0, *(const float4*)(de1 + dep * CD + c0));
                e1 = f4add(e1, *(const float4*)(de1 + dep * CD + c0 + 4));
                e0 = f4add(e0, *(const float4*)(se1 + (p0) * CD + c0));
                e1 = f4add(e1, *(const float4*)(se1 + (p0) * CD + c0 + 4));
                e0 = f4add(e0, *(const float4*)(se1 + (128 + p1) * CD + c0));
                e1 = f4add(e1, *(const float4*)(se1 + (128 + p1) * CD + c0 + 4));
                e0 = f4add(e0, *(const float4*)(se1 + (256 + p2) * CD + c0));
                e1 = f4add(e1, *(const float4*)(se1 + (256 + p2) * CD + c0 + 4));
            }
            Al[s][m] = e0.x;
            Al[8 + s][m] = e0.y;
            Al[16 + s][m] = e0.z;
            Al[24 + s][m] = e0.w;
            Al[32 + s][m] = e1.x;
            Al[40 + s][m] = e1.y;
            Al[48 + s][m] = e1.z;
            Al[56 + s][m] = e1.w;
        }
        // stage B: 64 k x 64 o
        for (int j = 0; j < 16; ++j) {
            int i = j * 256 + tid;
            int kl = i >> 6, o = i & 63;
            Bl[kl][o] = w1p[(ch * 64 + kl) * 256 + tn * 64 + o];
        }
        __syncthreads();
        int mo = (tid >> 4) * 4, oo = (tid & 15) * 4;
        #pragma unroll
        for (int kk = 0; kk < 64; ++kk) {
            float av[4], bv[4];
            *(float4*)av = *(const float4*)&Al[kk][mo];
            *(float4*)bv = *(const float4*)&Bl[kk][oo];
            #pragma unroll
            for (int i = 0; i < 4; ++i)
                #pragma unroll
                for (int j = 0; j < 4; ++j) acc[i][j] += av[i] * bv[j];
        }
        __syncthreads();
    }

    // epilogue: bias + store
    int mo = (tid >> 4) * 4, oo = tn * 64 + (tid & 15) * 4;
    float4 bias = *(const float4*)(b1 + oo);
    for (int i = 0; i < 4; ++i) {
        int g = g0 + mo + i;
        float4 r = make_float4(acc[i][0] + bias.x, acc[i][1] + bias.y,
                               acc[i][2] + bias.z, acc[i][3] + bias.w);
        *(float4*)(out + (size_t)g * O1 + oo) = r;
    }
}

// ---------------------------------------------------------------------------
extern "C" void kernel_launch(void* const* d_in, const int* in_sizes, int n_in,
                              void* d_out, int out_size, void* d_ws, size_t ws_size,
                              hipStream_t stream) {
    const int* value = (const int*)d_in[0];
    const int* depth = (const int*)d_in[1];
    const int* pos   = (const int*)d_in[2];
    const float* ve1 = (const float*)d_in[5];
    const float* de1 = (const float*)d_in[6];
    const float* se1 = (const float*)d_in[7];
    const float* ve2 = (const float*)d_in[8];
    const float* de2 = (const float*)d_in[9];
    const float* se2 = (const float*)d_in[10];
    const float* w1  = (const float*)d_in[11];
    const float* b1  = (const float*)d_in[12];
    const float* w2  = (const float*)d_in[13];
    const float* b2  = (const float*)d_in[14];
    float* out = (float*)d_out;

    char* ws = (char*)d_ws;
    float* w1p   = (float*)(ws);                               // 256 KB
    float* w2p   = (float*)(ws + 262144);                      // 32 KB
    float* y_c   = (float*)(ws + 294912);                      // 16 MB
    int*   order1= (int*)  (ws + 294912 + 16777216);           // 1 MB
    int*   dst2  = (int*)  (ws + 294912 + 16777216 + 1048576); // 512 KB

    hipMemsetAsync(y_c, 0, (size_t)BATCH * L2P * CD * sizeof(float), stream);
    k_pre<<<256, 256, 0, stream>>>(w1, w2, w1p, w2p);
    k_scan<<<BATCH, 256, 0, stream>>>(value, order1, dst2);
    k_conv2<<<1024, 256, 0, stream>>>(value, depth, pos, ve2, de2, se2,
                                      w2p, b2, dst2, y_c);
    k_conv1<<<dim3(512, 4), 256, 0, stream>>>(value, depth, pos, ve1, de1, se1,
                                              w1p, b1, order1, y_c, out);
}

// Round 2
// 109.781 us; speedup vs baseline: 1.7255x; 1.7255x over previous
//
#include <hip/hip_runtime.h>

// ---- problem constants (fixed by the reference) ----
#define BATCH   32
#define L1N     8192
#define L2N     32768
#define LTOT    40960
#define CD      32       // CONV_DEPTH
#define O1      256      // EMBED_DIM
#define L1P     1024     // L1N / 8
#define L2P     4096     // L2N / 8

typedef __attribute__((ext_vector_type(8))) short bf16x8;
typedef __attribute__((ext_vector_type(8))) unsigned short u16x8;
typedef __attribute__((ext_vector_type(4))) float f32x4;

__device__ __forceinline__ unsigned short f2bf(float f) {
    union { float f; unsigned u; } x; x.f = f;
    unsigned u = x.u + 0x7FFFu + ((x.u >> 16) & 1u);   // RNE
    return (unsigned short)(u >> 16);
}
__device__ __forceinline__ float4 f4add(float4 a, float4 b) {
    return make_float4(a.x + b.x, a.y + b.y, a.z + b.z, a.w + b.w);
}

// ---------------------------------------------------------------------------
// Pre-pass: permute+convert conv weights to bf16 [o][k] with k = s*32 + c.
// w1t[o*256 + s*32 + c] = conv1_w[o][c][s];  same for w2t (o<32).
// ---------------------------------------------------------------------------
__global__ void k_pre(const float* __restrict__ w1, const float* __restrict__ w2,
                      unsigned short* __restrict__ w1t, unsigned short* __restrict__ w2t) {
    int i = blockIdx.x * 256 + threadIdx.x;   // 65536 jobs
    if (i < 65536) {
        int o = i >> 8, k = i & 255, s = k >> 5, c = k & 31;
        w1t[i] = f2bf(w1[o * 256 + c * 8 + s]);
    }
    if (i < 8192) {
        int o = i >> 8, k = i & 255, s = k >> 5, c = k & 31;
        w2t[i] = f2bf(w2[o * 256 + c * 8 + s]);
    }
}

// ---------------------------------------------------------------------------
// Per-batch-row prefix sums: order1 (substitution gather index, -1 if not
// masked) over L1N; dst2 (compaction destination, -1 if dropped) over L2P.
// ---------------------------------------------------------------------------
__global__ void k_scan(const int* __restrict__ value,
                       int* __restrict__ order1, int* __restrict__ dst2) {
    int b = blockIdx.x, tid = threadIdx.x;
    __shared__ int part[256];

    const int* v1 = value + b * LTOT;
    int base = tid * 32;
    int cnt = 0;
    for (int i = 0; i < 32; ++i) cnt += (v1[base + i] == 2);
    part[tid] = cnt;
    __syncthreads();
    for (int off = 1; off < 256; off <<= 1) {
        int t = (tid >= off) ? part[tid - off] : 0;
        __syncthreads();
        part[tid] += t;
        __syncthreads();
    }
    int run = part[tid] - cnt;  // exclusive prefix
    for (int i = 0; i < 32; ++i) {
        int l = base + i;
        bool m = (v1[l] == 2);
        int ord = run < (L2P - 1) ? run : (L2P - 1);
        order1[b * L1N + l] = m ? ord : -1;
        run += m ? 1 : 0;
    }
    __syncthreads();

    const int* v2 = value + b * LTOT + L1N;
    int base2 = tid * 16;
    int cnt2 = 0;
    for (int i = 0; i < 16; ++i) cnt2 += (v2[(base2 + i) * 8] != 0);
    part[tid] = cnt2;
    __syncthreads();
    for (int off = 1; off < 256; off <<= 1) {
        int t = (tid >= off) ? part[tid - off] : 0;
        __syncthreads();
        part[tid] += t;
        __syncthreads();
    }
    int run2 = part[tid] - cnt2;
    for (int i = 0; i < 16; ++i) {
        int j = base2 + i;
        bool s = (v2[j * 8] != 0);
        dst2[b * L2P + j] = s ? run2 : -1;
        run2 += s ? 1 : 0;
    }
}

// ---------------------------------------------------------------------------
// conv2 (MFMA): fused embed2 -> LDS(bf16) -> GEMM M=131072,K=256,N=32 ->
// bias -> compact-scatter to y_c (bf16).  Block: 128Mx32N, 256 thr (4 waves).
// K chunked by 64 = 2 s-values; tokens partition cleanly across chunks.
// ---------------------------------------------------------------------------
__global__ __launch_bounds__(256) void k_conv2(
    const int* __restrict__ value, const int* __restrict__ depth,
    const int* __restrict__ pos,
    const float* __restrict__ ve2, const float* __restrict__ de2,
    const float* __restrict__ se2,
    const unsigned short* __restrict__ w2t, const float* __restrict__ b2,
    const int* __restrict__ dst2, unsigned short* __restrict__ y_c) {
    int tid = threadIdx.x, lane = tid & 63, wid = tid >> 6;
    int g0 = blockIdx.x * 128;
    __shared__ unsigned short As[128 * 64];   // [m][k-chunk], swizzled 16B chunks
    __shared__ unsigned short Bs[32 * 256];   // [n][k], swizzled
    f32x4 acc[2][2] = {};
    int m0 = wid * 32;

    // stage all of B once (16 KB)
    for (int it = 0; it < 4; ++it) {
        int idx = it * 256 + tid;             // 1024 chunks of 16 B
        int o = idx >> 5, c16 = idx & 31;
        u16x8 v = *(const u16x8*)(w2t + o * 256 + c16 * 8);
        *(u16x8*)&Bs[o * 256 + ((c16 ^ (o & 7)) * 8)] = v;
    }

    for (int kc = 0; kc < 4; ++kc) {
        if (kc) __syncthreads();              // previous reads done
        // ---- A-gen: 256 tokens (128 m x 2 s), 1 token/thread ----
        {
            int m = tid >> 1, sh = tid & 1, s = kc * 2 + sh;
            int g = g0 + m, b = g >> 12, l2 = g & (L2P - 1);
            int tok = b * LTOT + L1N + l2 * 8 + s;
            int val = value[tok], dep = depth[tok];
            const int* pp = pos + (size_t)tok * 3;
            int p0 = pp[0], p1 = pp[1] + 128, p2 = pp[2] + 256;
            const float4* tv = (const float4*)(ve2 + val * CD);
            const float4* td = (const float4*)(de2 + dep * CD);
            const float4* t0 = (const float4*)(se2 + p0 * CD);
            const float4* t1 = (const float4*)(se2 + p1 * CD);
            const float4* t2 = (const float4*)(se2 + p2 * CD);
            #pragma unroll
            for (int j = 0; j < 4; ++j) {     // 8 channels per iter
                float4 a = f4add(f4add(tv[j * 2], td[j * 2]),
                                 f4add(t0[j * 2], f4add(t1[j * 2], t2[j * 2])));
                float4 b4 = f4add(f4add(tv[j * 2 + 1], td[j * 2 + 1]),
                                  f4add(t0[j * 2 + 1], f4add(t1[j * 2 + 1], t2[j * 2 + 1])));
                u16x8 r;
                r[0] = f2bf(a.x); r[1] = f2bf(a.y); r[2] = f2bf(a.z); r[3] = f2bf(a.w);
                r[4] = f2bf(b4.x); r[5] = f2bf(b4.y); r[6] = f2bf(b4.z); r[7] = f2bf(b4.w);
                int c16 = sh * 4 + j;
                *(u16x8*)&As[m * 64 + ((c16 ^ (m & 7)) * 8)] = r;
            }
        }
        __syncthreads();
        // ---- MFMA ----
        #pragma unroll
        for (int ks = 0; ks < 2; ++ks) {
            int c16a = ks * 4 + (lane >> 4);
            int r0 = m0 + (lane & 15), r1 = r0 + 16;
            bf16x8 a0 = *(const bf16x8*)&As[r0 * 64 + ((c16a ^ (r0 & 7)) * 8)];
            bf16x8 a1 = *(const bf16x8*)&As[r1 * 64 + ((c16a ^ (r1 & 7)) * 8)];
            int c16b = kc * 8 + ks * 4 + (lane >> 4);
            #pragma unroll
            for (int nt = 0; nt < 2; ++nt) {
                int n = nt * 16 + (lane & 15);
                bf16x8 bv = *(const bf16x8*)&Bs[n * 256 + ((c16b ^ (n & 7)) * 8)];
                acc[0][nt] = __builtin_amdgcn_mfma_f32_16x16x32_bf16(a0, bv, acc[0][nt], 0, 0, 0);
                acc[1][nt] = __builtin_amdgcn_mfma_f32_16x16x32_bf16(a1, bv, acc[1][nt], 0, 0, 0);
            }
        }
    }

    // ---- epilogue: bias + compact scatter (bf16) ----
    #pragma unroll
    for (int mt = 0; mt < 2; ++mt)
        #pragma unroll
        for (int r = 0; r < 4; ++r) {
            int ml = m0 + mt * 16 + (lane >> 4) * 4 + r;
            int g = g0 + ml, b = g >> 12, l2 = g & (L2P - 1);
            int d = dst2[b * L2P + l2];
            if (d >= 0) {
                unsigned short* dst = y_c + ((size_t)(b * L2P + d)) * CD;
                #pragma unroll
                for (int nt = 0; nt < 2; ++nt) {
                    int n = nt * 16 + (lane & 15);
                    dst[n] = f2bf(acc[mt][nt][r] + b2[n]);
                }
            }
        }
}

// ---------------------------------------------------------------------------
// conv1 (MFMA): fused embed1 + substitution gather -> GEMM M=32768,K=256,N=256.
// Block: 128M x 256N (full N => A generated once), 512 thr (8 waves, 4Mx2N).
// ---------------------------------------------------------------------------
__global__ __launch_bounds__(512) void k_conv1(
    const int* __restrict__ value, const int* __restrict__ depth,
    const int* __restrict__ pos,
    const float* __restrict__ ve1, const float* __restrict__ de1,
    const float* __restrict__ se1,
    const unsigned short* __restrict__ w1t, const float* __restrict__ b1,
    const int* __restrict__ order1, const unsigned short* __restrict__ y_c,
    float* __restrict__ out) {
    int tid = threadIdx.x, lane = tid & 63, wid = tid >> 6;
    int g0 = blockIdx.x * 128;
    __shared__ unsigned short As[128 * 64];   // 16 KB
    __shared__ unsigned short Bs[256 * 64];   // 32 KB
    f32x4 acc[2][8] = {};
    int m0 = (wid >> 1) * 32, n0 = (wid & 1) * 128;

    for (int kc = 0; kc < 4; ++kc) {
        if (kc) __syncthreads();
        // ---- B stage: rows o=0..255, 16B chunk each of this K-chunk ----
        #pragma unroll
        for (int it = 0; it < 4; ++it) {
            int idx = it * 512 + tid;         // 2048 chunks
            int o = idx >> 3, c16 = idx & 7;
            u16x8 v = *(const u16x8*)(w1t + o * 256 + kc * 64 + c16 * 8);
            *(u16x8*)&Bs[o * 64 + ((c16 ^ (o & 7)) * 8)] = v;
        }
        // ---- A-gen: 256 tokens x 2 half-tokens (16 ch), 1 job/thread ----
        {
            int m = tid >> 2, sh = (tid >> 1) & 1, chh = tid & 1;
            int s = kc * 2 + sh, c0 = chh * 16;
            int g = g0 + m, b = g >> 10, l = g & (L1P - 1);
            int tokl = l * 8 + s, tok = b * LTOT + tokl;
            int val = value[tok];
            u16x8 r0v, r1v;
            if (val == 2) {
                int ord = order1[b * L1N + tokl];
                const unsigned short* src = y_c + ((size_t)(b * L2P + ord)) * CD + c0;
                r0v = *(const u16x8*)src;
                r1v = *(const u16x8*)(src + 8);
            } else {
                int dep = depth[tok];
                const int* pp = pos + (size_t)tok * 3;
                int p0 = pp[0], p1 = pp[1] + 128, p2 = pp[2] + 256;
                const float4* tv = (const float4*)(ve1 + val * CD + c0);
                const float4* td = (const float4*)(de1 + dep * CD + c0);
                const float4* t0 = (const float4*)(se1 + p0 * CD + c0);
                const float4* t1 = (const float4*)(se1 + p1 * CD + c0);
                const float4* t2 = (const float4*)(se1 + p2 * CD + c0);
                u16x8 rr[2];
                #pragma unroll
                for (int j = 0; j < 2; ++j) {
                    float4 a = f4add(f4add(tv[j * 2], td[j * 2]),
                                     f4add(t0[j * 2], f4add(t1[j * 2], t2[j * 2])));
                    float4 b4 = f4add(f4add(tv[j * 2 + 1], td[j * 2 + 1]),
                                      f4add(t0[j * 2 + 1], f4add(t1[j * 2 + 1], t2[j * 2 + 1])));
                    rr[j][0] = f2bf(a.x); rr[j][1] = f2bf(a.y); rr[j][2] = f2bf(a.z); rr[j][3] = f2bf(a.w);
                    rr[j][4] = f2bf(b4.x); rr[j][5] = f2bf(b4.y); rr[j][6] = f2bf(b4.z); rr[j][7] = f2bf(b4.w);
                }
                r0v = rr[0]; r1v = rr[1];
            }
            int cb = sh * 4 + chh * 2;
            *(u16x8*)&As[m * 64 + ((cb ^ (m & 7)) * 8)] = r0v;
            *(u16x8*)&As[m * 64 + (((cb + 1) ^ (m & 7)) * 8)] = r1v;
        }
        __syncthreads();
        // ---- MFMA: per wave 2M x 8N tiles x 2 K-steps ----
        #pragma unroll
        for (int ks = 0; ks < 2; ++ks) {
            int c16 = ks * 4 + (lane >> 4);
            int r0 = m0 + (lane & 15), r1 = r0 + 16;
            bf16x8 a0 = *(const bf16x8*)&As[r0 * 64 + ((c16 ^ (r0 & 7)) * 8)];
            bf16x8 a1 = *(const bf16x8*)&As[r1 * 64 + ((c16 ^ (r1 & 7)) * 8)];
            #pragma unroll
            for (int nt = 0; nt < 8; ++nt) {
                int n = n0 + nt * 16 + (lane & 15);
                bf16x8 bv = *(const bf16x8*)&Bs[n * 64 + ((c16 ^ (n & 7)) * 8)];
                acc[0][nt] = __builtin_amdgcn_mfma_f32_16x16x32_bf16(a0, bv, acc[0][nt], 0, 0, 0);
                acc[1][nt] = __builtin_amdgcn_mfma_f32_16x16x32_bf16(a1, bv, acc[1][nt], 0, 0, 0);
            }
        }
    }

    // ---- epilogue: bias + fp32 store ----
    #pragma unroll
    for (int nt = 0; nt < 8; ++nt) {
        int n = n0 + nt * 16 + (lane & 15);
        float bias = b1[n];
        #pragma unroll
        for (int mt = 0; mt < 2; ++mt)
            #pragma unroll
            for (int r = 0; r < 4; ++r) {
                int g = g0 + m0 + mt * 16 + (lane >> 4) * 4 + r;
                out[(size_t)g * O1 + n] = acc[mt][nt][r] + bias;
            }
    }
}

// ---------------------------------------------------------------------------
extern "C" void kernel_launch(void* const* d_in, const int* in_sizes, int n_in,
                              void* d_out, int out_size, void* d_ws, size_t ws_size,
                              hipStream_t stream) {
    const int* value = (const int*)d_in[0];
    const int* depth = (const int*)d_in[1];
    const int* pos   = (const int*)d_in[2];
    const float* ve1 = (const float*)d_in[5];
    const float* de1 = (const float*)d_in[6];
    const float* se1 = (const float*)d_in[7];
    const float* ve2 = (const float*)d_in[8];
    const float* de2 = (const float*)d_in[9];
    const float* se2 = (const float*)d_in[10];
    const float* w1  = (const float*)d_in[11];
    const float* b1  = (const float*)d_in[12];
    const float* w2  = (const float*)d_in[13];
    const float* b2  = (const float*)d_in[14];
    float* out = (float*)d_out;

    char* ws = (char*)d_ws;
    unsigned short* w1t = (unsigned short*)(ws);                      // 128 KB
    unsigned short* w2t = (unsigned short*)(ws + 131072);             // 16 KB
    unsigned short* y_c = (unsigned short*)(ws + 147456);             // 8 MB
    int* order1 = (int*)(ws + 147456 + 8388608);                      // 1 MB
    int* dst2   = (int*)(ws + 147456 + 8388608 + 1048576);            // 512 KB

    hipMemsetAsync(y_c, 0, 8388608, stream);
    k_pre<<<256, 256, 0, stream>>>(w1, w2, w1t, w2t);
    k_scan<<<BATCH, 256, 0, stream>>>(value, order1, dst2);
    k_conv2<<<1024, 256, 0, stream>>>(value, depth, pos, ve2, de2, se2,
                                      w2t, b2, dst2, y_c);
    k_conv1<<<256, 512, 0, stream>>>(value, depth, pos, ve1, de1, se1,
                                     w1t, b1, order1, y_c, out);
}

// Round 3
// 83.159 us; speedup vs baseline: 2.2780x; 1.3201x over previous
//
#include <hip/hip_runtime.h>

// ---- problem constants (fixed by the reference) ----
#define BATCH   32
#define L1N     8192
#define L2N     32768
#define LTOT    40960
#define CD      32       // CONV_DEPTH
#define O1      256      // EMBED_DIM
#define L1P     1024     // L1N / 8
#define L2P     4096     // L2N / 8

typedef __attribute__((ext_vector_type(8))) short bf16x8;
typedef __attribute__((ext_vector_type(8))) unsigned short u16x8;
typedef __attribute__((ext_vector_type(8))) _Float16 h16x8;
typedef __attribute__((ext_vector_type(4))) float f32x4;

__device__ __forceinline__ unsigned short f2bf(float f) {
    union { float f; unsigned u; } x; x.f = f;
    unsigned u = x.u + 0x7FFFu + ((x.u >> 16) & 1u);   // RNE
    return (unsigned short)(u >> 16);
}

// ---------------------------------------------------------------------------
// Pre-pass: weights -> bf16 [o][k], k = s*32+c;  embedding tables -> fp16.
// ---------------------------------------------------------------------------
__global__ void k_pre(const float* __restrict__ w1, const float* __restrict__ w2,
                      const float* __restrict__ ve1, const float* __restrict__ de1,
                      const float* __restrict__ se1, const float* __restrict__ ve2,
                      const float* __restrict__ de2, const float* __restrict__ se2,
                      unsigned short* __restrict__ w1t, unsigned short* __restrict__ w2t,
                      _Float16* __restrict__ ve1h, _Float16* __restrict__ de1h,
                      _Float16* __restrict__ se1h, _Float16* __restrict__ ve2h,
                      _Float16* __restrict__ de2h, _Float16* __restrict__ se2h) {
    int i = blockIdx.x * 256 + threadIdx.x;   // 65536 jobs
    if (i < 65536) {
        int o = i >> 8, k = i & 255, s = k >> 5, c = k & 31;
        w1t[i] = f2bf(w1[o * 256 + c * 8 + s]);
    }
    if (i < 8192) {
        int o = i >> 8, k = i & 255, s = k >> 5, c = k & 31;
        w2t[i] = f2bf(w2[o * 256 + c * 8 + s]);
    }
    if (i < 544) { ve1h[i] = (_Float16)ve1[i]; ve2h[i] = (_Float16)ve2[i]; }
    if (i < 224) { de1h[i] = (_Float16)de1[i]; de2h[i] = (_Float16)de2[i]; }
    if (i < 12288) { se1h[i] = (_Float16)se1[i]; se2h[i] = (_Float16)se2[i]; }
}

// ---------------------------------------------------------------------------
// Per-batch-row prefix sums via ballot (coalesced loads).
// order1: substitution gather index (-1 if unmasked) over L1N.
// dst2:   compaction destination (-1 if dropped) over L2P.
// ---------------------------------------------------------------------------
__global__ __launch_bounds__(256) void k_scan(const int* __restrict__ value,
                       int* __restrict__ order1, int* __restrict__ dst2) {
    int b = blockIdx.x, tid = threadIdx.x, lane = tid & 63, wid = tid >> 6;
    __shared__ int wsum[4];
    __shared__ int runsh;
    if (tid == 0) runsh = 0;
    __syncthreads();

    const int* v1 = value + b * LTOT;
    for (int c = 0; c < 32; ++c) {
        int idx = c * 256 + tid;
        bool m = (v1[idx] == 2);
        unsigned long long bal = __ballot(m);
        int lp = __popcll(bal & ((1ull << lane) - 1ull));
        if (lane == 0) wsum[wid] = __popcll(bal);
        __syncthreads();
        int off = runsh;
        for (int w = 0; w < 4; ++w) if (w < wid) off += wsum[w];
        int ord = off + lp;
        ord = ord < (L2P - 1) ? ord : (L2P - 1);
        order1[b * L1N + idx] = m ? ord : -1;
        __syncthreads();
        if (tid == 0) runsh += wsum[0] + wsum[1] + wsum[2] + wsum[3];
    }
    __syncthreads();
    if (tid == 0) runsh = 0;
    __syncthreads();

    const int* v2 = value + b * LTOT + L1N;
    for (int c = 0; c < 16; ++c) {
        int idx = c * 256 + tid;           // 0..4095
        bool s = (v2[idx * 8] != 0);
        unsigned long long bal = __ballot(s);
        int lp = __popcll(bal & ((1ull << lane) - 1ull));
        if (lane == 0) wsum[wid] = __popcll(bal);
        __syncthreads();
        int off = runsh;
        for (int w = 0; w < 4; ++w) if (w < wid) off += wsum[w];
        dst2[b * L2P + idx] = s ? (off + lp) : -1;
        __syncthreads();
        if (tid == 0) runsh += wsum[0] + wsum[1] + wsum[2] + wsum[3];
    }
}

// ---------------------------------------------------------------------------
// conv2 (MFMA): fused embed2 -> LDS(bf16) -> GEMM M=131072,K=256,N=32 ->
// bias -> compact-scatter to y_c (fp16).  Block: 128Mx32N, 256 thr (4 waves).
// A-gen uses 4-lane groups: each lane loads 16 B (8 ch) of the same 64 B row.
// ---------------------------------------------------------------------------
__global__ __launch_bounds__(256) void k_conv2(
    const int* __restrict__ value, const int* __restrict__ depth,
    const int* __restrict__ pos,
    const _Float16* __restrict__ ve2h, const _Float16* __restrict__ de2h,
    const _Float16* __restrict__ se2h,
    const unsigned short* __restrict__ w2t, const float* __restrict__ b2,
    const int* __restrict__ dst2, _Float16* __restrict__ y_c) {
    int tid = threadIdx.x, lane = tid & 63, wid = tid >> 6;
    int g0 = blockIdx.x * 128;
    __shared__ unsigned short As[128 * 64];   // 16 KB, swizzled 16B chunks
    __shared__ unsigned short Bs[32 * 256];   // 16 KB, swizzled
    f32x4 acc[2][2] = {};
    int m0 = wid * 32;
    int q = tid & 3;

    // stage all of B once
    for (int it = 0; it < 4; ++it) {
        int idx = it * 256 + tid;             // 1024 chunks of 16 B
        int o = idx >> 5, c16 = idx & 31;
        u16x8 v = *(const u16x8*)(w2t + o * 256 + c16 * 8);
        *(u16x8*)&Bs[o * 256 + ((c16 ^ (o & 7)) * 8)] = v;
    }

    for (int kc = 0; kc < 4; ++kc) {
        if (kc) __syncthreads();              // previous reads done
        // ---- A-gen: 256 tokens x 4 chunk-jobs, grouped gather ----
        #pragma unroll
        for (int r = 0; r < 4; ++r) {
            int t = r * 64 + (tid >> 2);      // token 0..255
            int m = t >> 1, sh = t & 1, s = kc * 2 + sh;
            int g = g0 + m, b = g >> 12, l2 = g & (L2P - 1);
            int tok = b * LTOT + L1N + l2 * 8 + s;
            int val = value[tok], dep = depth[tok];
            const int* pp = pos + (size_t)tok * 3;
            int p0 = pp[0], p1 = pp[1] + 128, p2 = pp[2] + 256;
            h16x8 v0 = *(const h16x8*)(ve2h + val * CD + q * 8);
            h16x8 v1 = *(const h16x8*)(de2h + dep * CD + q * 8);
            h16x8 v2 = *(const h16x8*)(se2h + p0 * CD + q * 8);
            h16x8 v3 = *(const h16x8*)(se2h + p1 * CD + q * 8);
            h16x8 v4 = *(const h16x8*)(se2h + p2 * CD + q * 8);
            u16x8 rr;
            #pragma unroll
            for (int j = 0; j < 8; ++j) {
                float sum = (float)v0[j] + (float)v1[j] + (float)v2[j]
                          + (float)v3[j] + (float)v4[j];
                rr[j] = f2bf(sum);
            }
            int c16 = sh * 4 + q;
            *(u16x8*)&As[m * 64 + ((c16 ^ (m & 7)) * 8)] = rr;
        }
        __syncthreads();
        // ---- MFMA ----
        #pragma unroll
        for (int ks = 0; ks < 2; ++ks) {
            int c16a = ks * 4 + (lane >> 4);
            int r0 = m0 + (lane & 15), r1 = r0 + 16;
            bf16x8 a0 = *(const bf16x8*)&As[r0 * 64 + ((c16a ^ (r0 & 7)) * 8)];
            bf16x8 a1 = *(const bf16x8*)&As[r1 * 64 + ((c16a ^ (r1 & 7)) * 8)];
            int c16b = kc * 8 + ks * 4 + (lane >> 4);
            #pragma unroll
            for (int nt = 0; nt < 2; ++nt) {
                int n = nt * 16 + (lane & 15);
                bf16x8 bv = *(const bf16x8*)&Bs[n * 256 + ((c16b ^ (n & 7)) * 8)];
                acc[0][nt] = __builtin_amdgcn_mfma_f32_16x16x32_bf16(a0, bv, acc[0][nt], 0, 0, 0);
                acc[1][nt] = __builtin_amdgcn_mfma_f32_16x16x32_bf16(a1, bv, acc[1][nt], 0, 0, 0);
            }
        }
    }

    // ---- epilogue: bias + compact scatter (fp16) ----
    #pragma unroll
    for (int mt = 0; mt < 2; ++mt)
        #pragma unroll
        for (int r = 0; r < 4; ++r) {
            int ml = m0 + mt * 16 + (lane >> 4) * 4 + r;
            int g = g0 + ml, b = g >> 12, l2 = g & (L2P - 1);
            int d = dst2[b * L2P + l2];
            if (d >= 0) {
                _Float16* dst = y_c + ((size_t)(b * L2P + d)) * CD;
                #pragma unroll
                for (int nt = 0; nt < 2; ++nt) {
                    int n = nt * 16 + (lane & 15);
                    dst[n] = (_Float16)(acc[mt][nt][r] + b2[n]);
                }
            }
        }
}

// ---------------------------------------------------------------------------
// conv1 (MFMA): fused embed1 + substitution gather -> GEMM M=32768,K=256,N=256.
// Block: 64M x 256N, 256 thr (4 waves, 2Mx2N wave grid of 32x128 tiles).
// Substitution unified: y_c row + zero rows (de[0]=se[*][0]=0) -> no branch.
// ---------------------------------------------------------------------------
__global__ __launch_bounds__(256) void k_conv1(
    const int* __restrict__ value, const int* __restrict__ depth,
    const int* __restrict__ pos,
    const _Float16* __restrict__ ve1h, const _Float16* __restrict__ de1h,
    const _Float16* __restrict__ se1h,
    const unsigned short* __restrict__ w1t, const float* __restrict__ b1,
    const int* __restrict__ order1, const _Float16* __restrict__ y_c,
    float* __restrict__ out) {
    int tid = threadIdx.x, lane = tid & 63, wid = tid >> 6;
    int g0 = blockIdx.x * 64;
    __shared__ unsigned short As[64 * 64];    // 8 KB
    __shared__ unsigned short Bs[256 * 64];   // 32 KB
    f32x4 acc[2][8] = {};
    int m0 = (wid & 1) * 32, n0 = (wid >> 1) * 128;
    int q = tid & 3;

    for (int kc = 0; kc < 4; ++kc) {
        if (kc) __syncthreads();
        // ---- B stage: 2048 16B chunks of this K-chunk ----
        #pragma unroll
        for (int it = 0; it < 8; ++it) {
            int idx = it * 256 + tid;
            int o = idx >> 3, c16 = idx & 7;
            u16x8 v = *(const u16x8*)(w1t + o * 256 + kc * 64 + c16 * 8);
            *(u16x8*)&Bs[o * 64 + ((c16 ^ (o & 7)) * 8)] = v;
        }
        // ---- A-gen: 128 tokens x 4 chunk-jobs, grouped gather ----
        #pragma unroll
        for (int r = 0; r < 2; ++r) {
            int t = r * 64 + (tid >> 2);      // token 0..127
            int m = t >> 1, sh = t & 1, s = kc * 2 + sh;
            int g = g0 + m, b = g >> 10, l = g & (L1P - 1);
            int tokl = l * 8 + s, tok = b * LTOT + tokl;
            int val = value[tok];
            bool sub = (val == 2);
            int ord = order1[b * L1N + tokl];
            int dep = sub ? 0 : depth[tok];
            const int* pp = pos + (size_t)tok * 3;
            int p0 = sub ? 0 : pp[0];
            int p1 = sub ? 128 : (pp[1] + 128);
            int p2 = sub ? 256 : (pp[2] + 256);
            const _Float16* base0 = sub
                ? (y_c + ((size_t)(b * L2P + ord)) * CD + q * 8)
                : (ve1h + val * CD + q * 8);
            h16x8 v0 = *(const h16x8*)base0;
            h16x8 v1 = *(const h16x8*)(de1h + dep * CD + q * 8);
            h16x8 v2 = *(const h16x8*)(se1h + p0 * CD + q * 8);
            h16x8 v3 = *(const h16x8*)(se1h + p1 * CD + q * 8);
            h16x8 v4 = *(const h16x8*)(se1h + p2 * CD + q * 8);
            u16x8 rr;
            #pragma unroll
            for (int j = 0; j < 8; ++j) {
                float sum = (float)v0[j] + (float)v1[j] + (float)v2[j]
                          + (float)v3[j] + (float)v4[j];
                rr[j] = f2bf(sum);
            }
            int c16 = sh * 4 + q;
            *(u16x8*)&As[m * 64 + ((c16 ^ (m & 7)) * 8)] = rr;
        }
        __syncthreads();
        // ---- MFMA: per wave 2M x 8N frags x 2 K-steps ----
        #pragma unroll
        for (int ks = 0; ks < 2; ++ks) {
            int c16 = ks * 4 + (lane >> 4);
            int r0 = m0 + (lane & 15), r1 = r0 + 16;
            bf16x8 a0 = *(const bf16x8*)&As[r0 * 64 + ((c16 ^ (r0 & 7)) * 8)];
            bf16x8 a1 = *(const bf16x8*)&As[r1 * 64 + ((c16 ^ (r1 & 7)) * 8)];
            #pragma unroll
            for (int nt = 0; nt < 8; ++nt) {
                int n = n0 + nt * 16 + (lane & 15);
                bf16x8 bv = *(const bf16x8*)&Bs[n * 64 + ((c16 ^ (n & 7)) * 8)];
                acc[0][nt] = __builtin_amdgcn_mfma_f32_16x16x32_bf16(a0, bv, acc[0][nt], 0, 0, 0);
                acc[1][nt] = __builtin_amdgcn_mfma_f32_16x16x32_bf16(a1, bv, acc[1][nt], 0, 0, 0);
            }
        }
    }

    // ---- epilogue: bias + fp32 store ----
    #pragma unroll
    for (int nt = 0; nt < 8; ++nt) {
        int n = n0 + nt * 16 + (lane & 15);
        float bias = b1[n];
        #pragma unroll
        for (int mt = 0; mt < 2; ++mt)
            #pragma unroll
            for (int r = 0; r < 4; ++r) {
                int g = g0 + m0 + mt * 16 + (lane >> 4) * 4 + r;
                out[(size_t)g * O1 + n] = acc[mt][nt][r] + bias;
            }
    }
}

// ---------------------------------------------------------------------------
extern "C" void kernel_launch(void* const* d_in, const int* in_sizes, int n_in,
                              void* d_out, int out_size, void* d_ws, size_t ws_size,
                              hipStream_t stream) {
    const int* value = (const int*)d_in[0];
    const int* depth = (const int*)d_in[1];
    const int* pos   = (const int*)d_in[2];
    const float* ve1 = (const float*)d_in[5];
    const float* de1 = (const float*)d_in[6];
    const float* se1 = (const float*)d_in[7];
    const float* ve2 = (const float*)d_in[8];
    const float* de2 = (const float*)d_in[9];
    const float* se2 = (const float*)d_in[10];
    const float* w1  = (const float*)d_in[11];
    const float* b1  = (const float*)d_in[12];
    const float* w2  = (const float*)d_in[13];
    const float* b2  = (const float*)d_in[14];
    float* out = (float*)d_out;

    char* ws = (char*)d_ws;
    unsigned short* w1t = (unsigned short*)(ws);              // 128 KB
    unsigned short* w2t = (unsigned short*)(ws + 131072);     // 16 KB
    _Float16* ve1h = (_Float16*)(ws + 147456);                // 4 KB slot
    _Float16* de1h = (_Float16*)(ws + 151552);                // 4 KB slot
    _Float16* se1h = (_Float16*)(ws + 155648);                // 24 KB
    _Float16* ve2h = (_Float16*)(ws + 180224);                // 4 KB slot
    _Float16* de2h = (_Float16*)(ws + 184320);                // 4 KB slot
    _Float16* se2h = (_Float16*)(ws + 188416);                // 24 KB
    _Float16* y_c  = (_Float16*)(ws + 212992);                // 8 MB
    int* order1 = (int*)(ws + 212992 + 8388608);              // 1 MB
    int* dst2   = (int*)(ws + 212992 + 8388608 + 1048576);    // 512 KB

    hipMemsetAsync(y_c, 0, 8388608, stream);
    k_pre<<<256, 256, 0, stream>>>(w1, w2, ve1, de1, se1, ve2, de2, se2,
                                   w1t, w2t, ve1h, de1h, se1h, ve2h, de2h, se2h);
    k_scan<<<BATCH, 256, 0, stream>>>(value, order1, dst2);
    k_conv2<<<1024, 256, 0, stream>>>(value, depth, pos, ve2h, de2h, se2h,
                                      w2t, b2, dst2, y_c);
    k_conv1<<<512, 256, 0, stream>>>(value, depth, pos, ve1h, de1h, se1h,
                                     w1t, b1, order1, y_c, out);
}

// Round 4
// 70.880 us; speedup vs baseline: 2.6726x; 1.1732x over previous
//
#include <hip/hip_runtime.h>

// ---- problem constants (fixed by the reference) ----
#define BATCH   32
#define L1N     8192
#define L2N     32768
#define LTOT    40960
#define CD      32       // CONV_DEPTH
#define O1      256      // EMBED_DIM
#define L1P     1024     // L1N / 8
#define L2P     4096     // L2N / 8

typedef __attribute__((ext_vector_type(8))) short bf16x8;
typedef __attribute__((ext_vector_type(8))) unsigned short u16x8;
typedef __attribute__((ext_vector_type(8))) _Float16 h16x8;
typedef __attribute__((ext_vector_type(4))) float f32x4;

__device__ __forceinline__ unsigned short f2bf(float f) {
    union { float f; unsigned u; } x; x.f = f;
    unsigned u = x.u + 0x7FFFu + ((x.u >> 16) & 1u);   // RNE
    return (unsigned short)(u >> 16);
}

// ---------------------------------------------------------------------------
// Pre-pass: weights -> bf16 [o][k], k = s*32+c;  embedding tables -> fp16.
// ---------------------------------------------------------------------------
__global__ void k_pre(const float* __restrict__ w1, const float* __restrict__ w2,
                      const float* __restrict__ ve1, const float* __restrict__ de1,
                      const float* __restrict__ se1, const float* __restrict__ ve2,
                      const float* __restrict__ de2, const float* __restrict__ se2,
                      unsigned short* __restrict__ w1t, unsigned short* __restrict__ w2t,
                      _Float16* __restrict__ ve1h, _Float16* __restrict__ de1h,
                      _Float16* __restrict__ se1h, _Float16* __restrict__ ve2h,
                      _Float16* __restrict__ de2h, _Float16* __restrict__ se2h) {
    int i = blockIdx.x * 256 + threadIdx.x;   // 65536 jobs
    if (i < 65536) {
        int o = i >> 8, k = i & 255, s = k >> 5, c = k & 31;
        w1t[i] = f2bf(w1[o * 256 + c * 8 + s]);
    }
    if (i < 8192) {
        int o = i >> 8, k = i & 255, s = k >> 5, c = k & 31;
        w2t[i] = f2bf(w2[o * 256 + c * 8 + s]);
    }
    if (i < 544) { ve1h[i] = (_Float16)ve1[i]; ve2h[i] = (_Float16)ve2[i]; }
    if (i < 224) { de1h[i] = (_Float16)de1[i]; de2h[i] = (_Float16)de2[i]; }
    if (i < 12288) { se1h[i] = (_Float16)se1[i]; se2h[i] = (_Float16)se2[i]; }
}

// ---------------------------------------------------------------------------
// Per-batch-row prefix sums via ballot.  grid = (BATCH, 2):
//   y==0: order1 (substitution gather index, -1 if unmasked) over L1N
//   y==1: dst2 (compaction destination, -1 if dropped) over L2P + cnt2[b]
// ---------------------------------------------------------------------------
__global__ __launch_bounds__(256) void k_scan(const int* __restrict__ value,
                       int* __restrict__ order1, int* __restrict__ dst2,
                       int* __restrict__ cnt2) {
    int b = blockIdx.x, tid = threadIdx.x, lane = tid & 63, wid = tid >> 6;
    __shared__ int wsum[4];
    __shared__ int runsh;
    if (tid == 0) runsh = 0;
    __syncthreads();

    if (blockIdx.y == 0) {
        const int* v1 = value + b * LTOT;
        for (int c = 0; c < 32; ++c) {
            int idx = c * 256 + tid;
            bool m = (v1[idx] == 2);
            unsigned long long bal = __ballot(m);
            int lp = __popcll(bal & ((1ull << lane) - 1ull));
            if (lane == 0) wsum[wid] = __popcll(bal);
            __syncthreads();
            int off = runsh;
            for (int w = 0; w < 4; ++w) if (w < wid) off += wsum[w];
            int ord = off + lp;
            ord = ord < (L2P - 1) ? ord : (L2P - 1);
            order1[b * L1N + idx] = m ? ord : -1;
            __syncthreads();
            if (tid == 0) runsh += wsum[0] + wsum[1] + wsum[2] + wsum[3];
        }
    } else {
        const int* v2 = value + b * LTOT + L1N;
        for (int c = 0; c < 16; ++c) {
            int idx = c * 256 + tid;           // 0..4095
            bool s = (v2[idx * 8] != 0);
            unsigned long long bal = __ballot(s);
            int lp = __popcll(bal & ((1ull << lane) - 1ull));
            if (lane == 0) wsum[wid] = __popcll(bal);
            __syncthreads();
            int off = runsh;
            for (int w = 0; w < 4; ++w) if (w < wid) off += wsum[w];
            dst2[b * L2P + idx] = s ? (off + lp) : -1;
            __syncthreads();
            if (tid == 0) runsh += wsum[0] + wsum[1] + wsum[2] + wsum[3];
        }
        if (tid == 0) cnt2[b] = runsh;   // tid0 made the last update itself
    }
}

// ---------------------------------------------------------------------------
// conv2 (MFMA): fused embed2 -> LDS(bf16) -> GEMM M=131072,K=256,N=32 ->
// bias -> compact-scatter to y_c (fp16).  Block: 128Mx32N, 256 thr (4 waves).
// A-gen uses 4-lane groups: each lane loads 16 B (8 ch) of the same 64 B row.
// y_c is NOT zero-initialized; rows >= cnt2[b] are garbage and never read.
// ---------------------------------------------------------------------------
__global__ __launch_bounds__(256) void k_conv2(
    const int* __restrict__ value, const int* __restrict__ depth,
    const int* __restrict__ pos,
    const _Float16* __restrict__ ve2h, const _Float16* __restrict__ de2h,
    const _Float16* __restrict__ se2h,
    const unsigned short* __restrict__ w2t, const float* __restrict__ b2,
    const int* __restrict__ dst2, _Float16* __restrict__ y_c) {
    int tid = threadIdx.x, lane = tid & 63, wid = tid >> 6;
    int g0 = blockIdx.x * 128;
    __shared__ unsigned short As[128 * 64];   // 16 KB, swizzled 16B chunks
    __shared__ unsigned short Bs[32 * 256];   // 16 KB, swizzled
    f32x4 acc[2][2] = {};
    int m0 = wid * 32;
    int q = tid & 3;

    // stage all of B once
    for (int it = 0; it < 4; ++it) {
        int idx = it * 256 + tid;             // 1024 chunks of 16 B
        int o = idx >> 5, c16 = idx & 31;
        u16x8 v = *(const u16x8*)(w2t + o * 256 + c16 * 8);
        *(u16x8*)&Bs[o * 256 + ((c16 ^ (o & 7)) * 8)] = v;
    }

    for (int kc = 0; kc < 4; ++kc) {
        if (kc) __syncthreads();              // previous reads done
        // ---- A-gen: 256 tokens x 4 chunk-jobs, grouped gather ----
        #pragma unroll
        for (int r = 0; r < 4; ++r) {
            int t = r * 64 + (tid >> 2);      // token 0..255
            int m = t >> 1, sh = t & 1, s = kc * 2 + sh;
            int g = g0 + m, b = g >> 12, l2 = g & (L2P - 1);
            int tok = b * LTOT + L1N + l2 * 8 + s;
            int val = value[tok], dep = depth[tok];
            const int* pp = pos + (size_t)tok * 3;
            int p0 = pp[0], p1 = pp[1] + 128, p2 = pp[2] + 256;
            h16x8 v0 = *(const h16x8*)(ve2h + val * CD + q * 8);
            h16x8 v1 = *(const h16x8*)(de2h + dep * CD + q * 8);
            h16x8 v2 = *(const h16x8*)(se2h + p0 * CD + q * 8);
            h16x8 v3 = *(const h16x8*)(se2h + p1 * CD + q * 8);
            h16x8 v4 = *(const h16x8*)(se2h + p2 * CD + q * 8);
            u16x8 rr;
            #pragma unroll
            for (int j = 0; j < 8; ++j) {
                float sum = (float)v0[j] + (float)v1[j] + (float)v2[j]
                          + (float)v3[j] + (float)v4[j];
                rr[j] = f2bf(sum);
            }
            int c16 = sh * 4 + q;
            *(u16x8*)&As[m * 64 + ((c16 ^ (m & 7)) * 8)] = rr;
        }
        __syncthreads();
        // ---- MFMA ----
        #pragma unroll
        for (int ks = 0; ks < 2; ++ks) {
            int c16a = ks * 4 + (lane >> 4);
            int r0 = m0 + (lane & 15), r1 = r0 + 16;
            bf16x8 a0 = *(const bf16x8*)&As[r0 * 64 + ((c16a ^ (r0 & 7)) * 8)];
            bf16x8 a1 = *(const bf16x8*)&As[r1 * 64 + ((c16a ^ (r1 & 7)) * 8)];
            int c16b = kc * 8 + ks * 4 + (lane >> 4);
            #pragma unroll
            for (int nt = 0; nt < 2; ++nt) {
                int n = nt * 16 + (lane & 15);
                bf16x8 bv = *(const bf16x8*)&Bs[n * 256 + ((c16b ^ (n & 7)) * 8)];
                acc[0][nt] = __builtin_amdgcn_mfma_f32_16x16x32_bf16(a0, bv, acc[0][nt], 0, 0, 0);
                acc[1][nt] = __builtin_amdgcn_mfma_f32_16x16x32_bf16(a1, bv, acc[1][nt], 0, 0, 0);
            }
        }
    }

    // ---- epilogue: bias + compact scatter (fp16) ----
    #pragma unroll
    for (int mt = 0; mt < 2; ++mt)
        #pragma unroll
        for (int r = 0; r < 4; ++r) {
            int ml = m0 + mt * 16 + (lane >> 4) * 4 + r;
            int g = g0 + ml, b = g >> 12, l2 = g & (L2P - 1);
            int d = dst2[b * L2P + l2];
            if (d >= 0) {
                _Float16* dst = y_c + ((size_t)(b * L2P + d)) * CD;
                #pragma unroll
                for (int nt = 0; nt < 2; ++nt) {
                    int n = nt * 16 + (lane & 15);
                    dst[n] = (_Float16)(acc[mt][nt][r] + b2[n]);
                }
            }
        }
}

// ---------------------------------------------------------------------------
// conv1 (MFMA): fused embed1 + substitution gather -> GEMM M=32768,K=256,N=256.
// Block: 64M x 256N, 256 thr (4 waves, 2Mx2N wave grid of 32x128 tiles).
// Substitution: valid ord -> y_c row; ord >= cnt2[b] -> zero rows (row 0 of
// each table is all-zero by construction).
// ---------------------------------------------------------------------------
__global__ __launch_bounds__(256) void k_conv1(
    const int* __restrict__ value, const int* __restrict__ depth,
    const int* __restrict__ pos,
    const _Float16* __restrict__ ve1h, const _Float16* __restrict__ de1h,
    const _Float16* __restrict__ se1h,
    const unsigned short* __restrict__ w1t, const float* __restrict__ b1,
    const int* __restrict__ order1, const int* __restrict__ cnt2,
    const _Float16* __restrict__ y_c, float* __restrict__ out) {
    int tid = threadIdx.x, lane = tid & 63, wid = tid >> 6;
    int g0 = blockIdx.x * 64;
    __shared__ unsigned short As[64 * 64];    // 8 KB
    __shared__ unsigned short Bs[256 * 64];   // 32 KB
    f32x4 acc[2][8] = {};
    int m0 = (wid & 1) * 32, n0 = (wid >> 1) * 128;
    int q = tid & 3;
    int c2 = cnt2[g0 >> 10];                  // 64 m-rows stay in one batch

    for (int kc = 0; kc < 4; ++kc) {
        if (kc) __syncthreads();
        // ---- B stage: 2048 16B chunks of this K-chunk ----
        #pragma unroll
        for (int it = 0; it < 8; ++it) {
            int idx = it * 256 + tid;
            int o = idx >> 3, c16 = idx & 7;
            u16x8 v = *(const u16x8*)(w1t + o * 256 + kc * 64 + c16 * 8);
            *(u16x8*)&Bs[o * 64 + ((c16 ^ (o & 7)) * 8)] = v;
        }
        // ---- A-gen: 128 tokens x 4 chunk-jobs, grouped gather ----
        #pragma unroll
        for (int r = 0; r < 2; ++r) {
            int t = r * 64 + (tid >> 2);      // token 0..127
            int m = t >> 1, sh = t & 1, s = kc * 2 + sh;
            int g = g0 + m, b = g >> 10, l = g & (L1P - 1);
            int tokl = l * 8 + s, tok = b * LTOT + tokl;
            int val = value[tok];
            bool sub = (val == 2);
            int ord = order1[b * L1N + tokl];
            bool valid = sub && (ord < c2);
            int dep = sub ? 0 : depth[tok];
            const int* pp = pos + (size_t)tok * 3;
            int p0 = sub ? 0 : pp[0];
            int p1 = sub ? 128 : (pp[1] + 128);
            int p2 = sub ? 256 : (pp[2] + 256);
            const _Float16* base0 =
                valid ? (y_c + ((size_t)(b * L2P + ord)) * CD + q * 8)
                      : (ve1h + (sub ? 0 : val * CD) + q * 8);
            h16x8 v0 = *(const h16x8*)base0;
            h16x8 v1 = *(const h16x8*)(de1h + dep * CD + q * 8);
            h16x8 v2 = *(const h16x8*)(se1h + p0 * CD + q * 8);
            h16x8 v3 = *(const h16x8*)(se1h + p1 * CD + q * 8);
            h16x8 v4 = *(const h16x8*)(se1h + p2 * CD + q * 8);
            u16x8 rr;
            #pragma unroll
            for (int j = 0; j < 8; ++j) {
                float sum = (float)v0[j] + (float)v1[j] + (float)v2[j]
                          + (float)v3[j] + (float)v4[j];
                rr[j] = f2bf(sum);
            }
            int c16 = sh * 4 + q;
            *(u16x8*)&As[m * 64 + ((c16 ^ (m & 7)) * 8)] = rr;
        }
        __syncthreads();
        // ---- MFMA: per wave 2M x 8N frags x 2 K-steps ----
        #pragma unroll
        for (int ks = 0; ks < 2; ++ks) {
            int c16 = ks * 4 + (lane >> 4);
            int r0 = m0 + (lane & 15), r1 = r0 + 16;
            bf16x8 a0 = *(const bf16x8*)&As[r0 * 64 + ((c16 ^ (r0 & 7)) * 8)];
            bf16x8 a1 = *(const bf16x8*)&As[r1 * 64 + ((c16 ^ (r1 & 7)) * 8)];
            #pragma unroll
            for (int nt = 0; nt < 8; ++nt) {
                int n = n0 + nt * 16 + (lane & 15);
                bf16x8 bv = *(const bf16x8*)&Bs[n * 64 + ((c16 ^ (n & 7)) * 8)];
                acc[0][nt] = __builtin_amdgcn_mfma_f32_16x16x32_bf16(a0, bv, acc[0][nt], 0, 0, 0);
                acc[1][nt] = __builtin_amdgcn_mfma_f32_16x16x32_bf16(a1, bv, acc[1][nt], 0, 0, 0);
            }
        }
    }

    // ---- epilogue: bias + fp32 store ----
    #pragma unroll
    for (int nt = 0; nt < 8; ++nt) {
        int n = n0 + nt * 16 + (lane & 15);
        float bias = b1[n];
        #pragma unroll
        for (int mt = 0; mt < 2; ++mt)
            #pragma unroll
            for (int r = 0; r < 4; ++r) {
                int g = g0 + m0 + mt * 16 + (lane >> 4) * 4 + r;
                out[(size_t)g * O1 + n] = acc[mt][nt][r] + bias;
            }
    }
}

// ---------------------------------------------------------------------------
extern "C" void kernel_launch(void* const* d_in, const int* in_sizes, int n_in,
                              void* d_out, int out_size, void* d_ws, size_t ws_size,
                              hipStream_t stream) {
    const int* value = (const int*)d_in[0];
    const int* depth = (const int*)d_in[1];
    const int* pos   = (const int*)d_in[2];
    const float* ve1 = (const float*)d_in[5];
    const float* de1 = (const float*)d_in[6];
    const float* se1 = (const float*)d_in[7];
    const float* ve2 = (const float*)d_in[8];
    const float* de2 = (const float*)d_in[9];
    const float* se2 = (const float*)d_in[10];
    const float* w1  = (const float*)d_in[11];
    const float* b1  = (const float*)d_in[12];
    const float* w2  = (const float*)d_in[13];
    const float* b2  = (const float*)d_in[14];
    float* out = (float*)d_out;

    char* ws = (char*)d_ws;
    unsigned short* w1t = (unsigned short*)(ws);              // 128 KB
    unsigned short* w2t = (unsigned short*)(ws + 131072);     // 16 KB
    _Float16* ve1h = (_Float16*)(ws + 147456);                // 4 KB slot
    _Float16* de1h = (_Float16*)(ws + 151552);                // 4 KB slot
    _Float16* se1h = (_Float16*)(ws + 155648);                // 24 KB
    _Float16* ve2h = (_Float16*)(ws + 180224);                // 4 KB slot
    _Float16* de2h = (_Float16*)(ws + 184320);                // 4 KB slot
    _Float16* se2h = (_Float16*)(ws + 188416);                // 24 KB
    _Float16* y_c  = (_Float16*)(ws + 212992);                // 8 MB
    int* order1 = (int*)(ws + 212992 + 8388608);              // 1 MB
    int* dst2   = (int*)(ws + 212992 + 8388608 + 1048576);    // 512 KB
    int* cnt2   = (int*)(ws + 212992 + 8388608 + 1048576 + 524288); // 128 B

    k_pre<<<256, 256, 0, stream>>>(w1, w2, ve1, de1, se1, ve2, de2, se2,
                                   w1t, w2t, ve1h, de1h, se1h, ve2h, de2h, se2h);
    k_scan<<<dim3(BATCH, 2), 256, 0, stream>>>(value, order1, dst2, cnt2);
    k_conv2<<<1024, 256, 0, stream>>>(value, depth, pos, ve2h, de2h, se2h,
                                      w2t, b2, dst2, y_c);
    k_conv1<<<512, 256, 0, stream>>>(value, depth, pos, ve1h, de1h, se1h,
                                     w1t, b1, order1, cnt2, y_c, out);
}

// Round 5
// 56.322 us; speedup vs baseline: 3.3634x; 1.2585x over previous
//
#include <hip/hip_runtime.h>

// ---- problem constants (fixed by the reference) ----
#define BATCH   32
#define L1N     8192
#define L2N     32768
#define LTOT    40960
#define CD      32       // CONV_DEPTH
#define O1      256      // EMBED_DIM
#define L1P     1024     // L1N / 8
#define L2P     4096     // L2N / 8

typedef __attribute__((ext_vector_type(8))) _Float16 h16x8;
typedef __attribute__((ext_vector_type(8))) unsigned short u16x8;
typedef __attribute__((ext_vector_type(4))) float f32x4;

// ---------------------------------------------------------------------------
// Pre-pass: weights -> fp16 [o][k], k = s*32+c;  embedding tables -> fp16.
// ---------------------------------------------------------------------------
__global__ void k_pre(const float* __restrict__ w1, const float* __restrict__ w2,
                      const float* __restrict__ ve1, const float* __restrict__ de1,
                      const float* __restrict__ se1, const float* __restrict__ ve2,
                      const float* __restrict__ de2, const float* __restrict__ se2,
                      _Float16* __restrict__ w1h, _Float16* __restrict__ w2h,
                      _Float16* __restrict__ ve1h, _Float16* __restrict__ de1h,
                      _Float16* __restrict__ se1h, _Float16* __restrict__ ve2h,
                      _Float16* __restrict__ de2h, _Float16* __restrict__ se2h) {
    int i = blockIdx.x * 256 + threadIdx.x;   // 65536 jobs
    if (i < 65536) {
        int o = i >> 8, k = i & 255, s = k >> 5, c = k & 31;
        w1h[i] = (_Float16)w1[o * 256 + c * 8 + s];
    }
    if (i < 8192) {
        int o = i >> 8, k = i & 255, s = k >> 5, c = k & 31;
        w2h[i] = (_Float16)w2[o * 256 + c * 8 + s];
    }
    if (i < 544) { ve1h[i] = (_Float16)ve1[i]; ve2h[i] = (_Float16)ve2[i]; }
    if (i < 224) { de1h[i] = (_Float16)de1[i]; de2h[i] = (_Float16)de2[i]; }
    if (i < 12288) { se1h[i] = (_Float16)se1[i]; se2h[i] = (_Float16)se2[i]; }
}

// ---------------------------------------------------------------------------
// Per-batch-row prefix sums, register-resident two-phase scan.
// grid = (BATCH, 2):  y==0 -> order1 over L1N;  y==1 -> dst2 over L2P + cnt2.
// Thread t owns a CONTIGUOUS range (order preserved); wave shfl-scan +
// cross-wave LDS scan gives each thread its exclusive base.
// ---------------------------------------------------------------------------
__global__ __launch_bounds__(256) void k_scan(const int* __restrict__ value,
                       int* __restrict__ order1, int* __restrict__ dst2,
                       int* __restrict__ cnt2) {
    int b = blockIdx.x, tid = threadIdx.x, lane = tid & 63, wid = tid >> 6;
    __shared__ int wsum[4];

    if (blockIdx.y == 0) {
        const int4* v = (const int4*)(value + b * LTOT) + tid * 8;  // 32 ints
        int4 r[8];
        #pragma unroll
        for (int j = 0; j < 8; ++j) r[j] = v[j];
        int cnt = 0;
        #pragma unroll
        for (int j = 0; j < 8; ++j)
            cnt += (r[j].x == 2) + (r[j].y == 2) + (r[j].z == 2) + (r[j].w == 2);
        int sc = cnt;
        #pragma unroll
        for (int d = 1; d < 64; d <<= 1) {
            int t = __shfl_up(sc, d);
            if (lane >= d) sc += t;
        }
        if (lane == 63) wsum[wid] = sc;
        __syncthreads();
        int base = 0;
        for (int w = 0; w < 4; ++w) if (w < wid) base += wsum[w];
        int run = base + sc - cnt;             // exclusive prefix
        int4* o = (int4*)(order1 + b * L1N + tid * 32);
        #pragma unroll
        for (int j = 0; j < 8; ++j) {
            int vv[4] = {r[j].x, r[j].y, r[j].z, r[j].w};
            int ot[4];
            #pragma unroll
            for (int i = 0; i < 4; ++i) {
                bool m = (vv[i] == 2);
                int ord = run < (L2P - 1) ? run : (L2P - 1);
                ot[i] = m ? ord : -1;
                run += m;
            }
            o[j] = make_int4(ot[0], ot[1], ot[2], ot[3]);
        }
    } else {
        const int* v2 = value + b * LTOT + L1N + tid * 16 * 8;
        int m[16]; int cnt = 0;
        #pragma unroll
        for (int i = 0; i < 16; ++i) { m[i] = (v2[i * 8] != 0); cnt += m[i]; }
        int sc = cnt;
        #pragma unroll
        for (int d = 1; d < 64; d <<= 1) {
            int t = __shfl_up(sc, d);
            if (lane >= d) sc += t;
        }
        if (lane == 63) wsum[wid] = sc;
        __syncthreads();
        int base = 0;
        for (int w = 0; w < 4; ++w) if (w < wid) base += wsum[w];
        int run = base + sc - cnt;
        int* o = dst2 + b * L2P + tid * 16;
        #pragma unroll
        for (int i = 0; i < 16; i += 4) {
            int ot[4];
            #pragma unroll
            for (int k2 = 0; k2 < 4; ++k2) { ot[k2] = m[i + k2] ? run : -1; run += m[i + k2]; }
            *(int4*)(o + i) = make_int4(ot[0], ot[1], ot[2], ot[3]);
        }
        if (tid == 255) cnt2[b] = base + sc;   // grand total
    }
}

// ---------------------------------------------------------------------------
// conv2 (MFMA f16): fused embed2 -> LDS(fp16) -> GEMM M=131072,K=256,N=32 ->
// bias -> compact-scatter to y_c (fp16).  Block: 128Mx32N, 256 thr (4 waves).
// A-gen: 4-lane groups, packed fp16 adds, no format conversions anywhere.
// y_c is NOT zero-initialized; rows >= cnt2[b] are garbage and never read.
// ---------------------------------------------------------------------------
__global__ __launch_bounds__(256) void k_conv2(
    const int* __restrict__ value, const int* __restrict__ depth,
    const int* __restrict__ pos,
    const _Float16* __restrict__ ve2h, const _Float16* __restrict__ de2h,
    const _Float16* __restrict__ se2h,
    const _Float16* __restrict__ w2h, const float* __restrict__ b2,
    const int* __restrict__ dst2, _Float16* __restrict__ y_c) {
    int tid = threadIdx.x, lane = tid & 63, wid = tid >> 6;
    int g0 = blockIdx.x * 128;
    __shared__ _Float16 As[128 * 64];   // 16 KB, swizzled 16B chunks
    __shared__ _Float16 Bs[32 * 256];   // 16 KB, swizzled
    f32x4 acc[2][2] = {};
    int m0 = wid * 32;
    int q = tid & 3;

    // stage all of B once
    for (int it = 0; it < 4; ++it) {
        int idx = it * 256 + tid;             // 1024 chunks of 16 B
        int o = idx >> 5, c16 = idx & 31;
        h16x8 v = *(const h16x8*)(w2h + o * 256 + c16 * 8);
        *(h16x8*)&Bs[o * 256 + ((c16 ^ (o & 7)) * 8)] = v;
    }

    for (int kc = 0; kc < 4; ++kc) {
        if (kc) __syncthreads();              // previous reads done
        // ---- A-gen: 256 tokens x 4 chunk-jobs, grouped gather ----
        #pragma unroll
        for (int r = 0; r < 4; ++r) {
            int t = r * 64 + (tid >> 2);      // token 0..255
            int m = t >> 1, sh = t & 1, s = kc * 2 + sh;
            int g = g0 + m, b = g >> 12, l2 = g & (L2P - 1);
            int tok = b * LTOT + L1N + l2 * 8 + s;
            int val = value[tok], dep = depth[tok];
            const int* pp = pos + (size_t)tok * 3;
            int p0 = pp[0], p1 = pp[1] + 128, p2 = pp[2] + 256;
            h16x8 v0 = *(const h16x8*)(ve2h + val * CD + q * 8);
            h16x8 v1 = *(const h16x8*)(de2h + dep * CD + q * 8);
            h16x8 v2 = *(const h16x8*)(se2h + p0 * CD + q * 8);
            h16x8 v3 = *(const h16x8*)(se2h + p1 * CD + q * 8);
            h16x8 v4 = *(const h16x8*)(se2h + p2 * CD + q * 8);
            h16x8 sum = (v0 + v1) + (v2 + v3) + v4;   // packed fp16 adds
            int c16 = sh * 4 + q;
            *(h16x8*)&As[m * 64 + ((c16 ^ (m & 7)) * 8)] = sum;
        }
        __syncthreads();
        // ---- MFMA ----
        #pragma unroll
        for (int ks = 0; ks < 2; ++ks) {
            int c16a = ks * 4 + (lane >> 4);
            int r0 = m0 + (lane & 15), r1 = r0 + 16;
            h16x8 a0 = *(const h16x8*)&As[r0 * 64 + ((c16a ^ (r0 & 7)) * 8)];
            h16x8 a1 = *(const h16x8*)&As[r1 * 64 + ((c16a ^ (r1 & 7)) * 8)];
            int c16b = kc * 8 + ks * 4 + (lane >> 4);
            #pragma unroll
            for (int nt = 0; nt < 2; ++nt) {
                int n = nt * 16 + (lane & 15);
                h16x8 bv = *(const h16x8*)&Bs[n * 256 + ((c16b ^ (n & 7)) * 8)];
                acc[0][nt] = __builtin_amdgcn_mfma_f32_16x16x32_f16(a0, bv, acc[0][nt], 0, 0, 0);
                acc[1][nt] = __builtin_amdgcn_mfma_f32_16x16x32_f16(a1, bv, acc[1][nt], 0, 0, 0);
            }
        }
    }

    // ---- epilogue: bias + compact scatter (fp16) ----
    #pragma unroll
    for (int mt = 0; mt < 2; ++mt)
        #pragma unroll
        for (int r = 0; r < 4; ++r) {
            int ml = m0 + mt * 16 + (lane >> 4) * 4 + r;
            int g = g0 + ml, b = g >> 12, l2 = g & (L2P - 1);
            int d = dst2[b * L2P + l2];
            if (d >= 0) {
                _Float16* dst = y_c + ((size_t)(b * L2P + d)) * CD;
                #pragma unroll
                for (int nt = 0; nt < 2; ++nt) {
                    int n = nt * 16 + (lane & 15);
                    dst[n] = (_Float16)(acc[mt][nt][r] + b2[n]);
                }
            }
        }
}

// ---------------------------------------------------------------------------
// conv1 (MFMA f16): fused embed1 + substitution gather -> GEMM M=32768,K=256,
// N=256.  Block: 64M x 256N, 256 thr (4 waves).  Substitution: valid ord ->
// y_c row (fp16, direct); ord >= cnt2[b] -> all-zero table rows.
// ---------------------------------------------------------------------------
__global__ __launch_bounds__(256) void k_conv1(
    const int* __restrict__ value, const int* __restrict__ depth,
    const int* __restrict__ pos,
    const _Float16* __restrict__ ve1h, const _Float16* __restrict__ de1h,
    const _Float16* __restrict__ se1h,
    const _Float16* __restrict__ w1h, const float* __restrict__ b1,
    const int* __restrict__ order1, const int* __restrict__ cnt2,
    const _Float16* __restrict__ y_c, float* __restrict__ out) {
    int tid = threadIdx.x, lane = tid & 63, wid = tid >> 6;
    int g0 = blockIdx.x * 64;
    __shared__ _Float16 As[64 * 64];    // 8 KB
    __shared__ _Float16 Bs[256 * 64];   // 32 KB
    f32x4 acc[2][8] = {};
    int m0 = (wid & 1) * 32, n0 = (wid >> 1) * 128;
    int q = tid & 3;
    int c2 = cnt2[g0 >> 10];            // 64 m-rows stay within one batch

    for (int kc = 0; kc < 4; ++kc) {
        if (kc) __syncthreads();
        // ---- B stage: 2048 16B chunks of this K-chunk ----
        #pragma unroll
        for (int it = 0; it < 8; ++it) {
            int idx = it * 256 + tid;
            int o = idx >> 3, c16 = idx & 7;
            h16x8 v = *(const h16x8*)(w1h + o * 256 + kc * 64 + c16 * 8);
            *(h16x8*)&Bs[o * 64 + ((c16 ^ (o & 7)) * 8)] = v;
        }
        // ---- A-gen: 128 tokens x 4 chunk-jobs, grouped gather ----
        #pragma unroll
        for (int r = 0; r < 2; ++r) {
            int t = r * 64 + (tid >> 2);      // token 0..127
            int m = t >> 1, sh = t & 1, s = kc * 2 + sh;
            int g = g0 + m, b = g >> 10, l = g & (L1P - 1);
            int tokl = l * 8 + s, tok = b * LTOT + tokl;
            int val = value[tok];
            bool sub = (val == 2);
            int ord = order1[b * L1N + tokl];
            bool valid = sub && (ord < c2);
            int dep = sub ? 0 : depth[tok];
            const int* pp = pos + (size_t)tok * 3;
            int p0 = sub ? 0 : pp[0];
            int p1 = sub ? 128 : (pp[1] + 128);
            int p2 = sub ? 256 : (pp[2] + 256);
            const _Float16* base0 =
                valid ? (y_c + ((size_t)(b * L2P + ord)) * CD + q * 8)
                      : (ve1h + (sub ? 0 : val * CD) + q * 8);
            h16x8 v0 = *(const h16x8*)base0;
            h16x8 v1 = *(const h16x8*)(de1h + dep * CD + q * 8);
            h16x8 v2 = *(const h16x8*)(se1h + p0 * CD + q * 8);
            h16x8 v3 = *(const h16x8*)(se1h + p1 * CD + q * 8);
            h16x8 v4 = *(const h16x8*)(se1h + p2 * CD + q * 8);
            h16x8 sum = (v0 + v1) + (v2 + v3) + v4;
            int c16 = sh * 4 + q;
            *(h16x8*)&As[m * 64 + ((c16 ^ (m & 7)) * 8)] = sum;
        }
        __syncthreads();
        // ---- MFMA: per wave 2M x 8N frags x 2 K-steps ----
        #pragma unroll
        for (int ks = 0; ks < 2; ++ks) {
            int c16 = ks * 4 + (lane >> 4);
            int r0 = m0 + (lane & 15), r1 = r0 + 16;
            h16x8 a0 = *(const h16x8*)&As[r0 * 64 + ((c16 ^ (r0 & 7)) * 8)];
            h16x8 a1 = *(const h16x8*)&As[r1 * 64 + ((c16 ^ (r1 & 7)) * 8)];
            #pragma unroll
            for (int nt = 0; nt < 8; ++nt) {
                int n = n0 + nt * 16 + (lane & 15);
                h16x8 bv = *(const h16x8*)&Bs[n * 64 + ((c16 ^ (n & 7)) * 8)];
                acc[0][nt] = __builtin_amdgcn_mfma_f32_16x16x32_f16(a0, bv, acc[0][nt], 0, 0, 0);
                acc[1][nt] = __builtin_amdgcn_mfma_f32_16x16x32_f16(a1, bv, acc[1][nt], 0, 0, 0);
            }
        }
    }

    // ---- epilogue: bias + fp32 store ----
    #pragma unroll
    for (int nt = 0; nt < 8; ++nt) {
        int n = n0 + nt * 16 + (lane & 15);
        float bias = b1[n];
        #pragma unroll
        for (int mt = 0; mt < 2; ++mt)
            #pragma unroll
            for (int r = 0; r < 4; ++r) {
                int g = g0 + m0 + mt * 16 + (lane >> 4) * 4 + r;
                out[(size_t)g * O1 + n] = acc[mt][nt][r] + bias;
            }
    }
}

// ---------------------------------------------------------------------------
extern "C" void kernel_launch(void* const* d_in, const int* in_sizes, int n_in,
                              void* d_out, int out_size, void* d_ws, size_t ws_size,
                              hipStream_t stream) {
    const int* value = (const int*)d_in[0];
    const int* depth = (const int*)d_in[1];
    const int* pos   = (const int*)d_in[2];
    const float* ve1 = (const float*)d_in[5];
    const float* de1 = (const float*)d_in[6];
    const float* se1 = (const float*)d_in[7];
    const float* ve2 = (const float*)d_in[8];
    const float* de2 = (const float*)d_in[9];
    const float* se2 = (const float*)d_in[10];
    const float* w1  = (const float*)d_in[11];
    const float* b1  = (const float*)d_in[12];
    const float* w2  = (const float*)d_in[13];
    const float* b2  = (const float*)d_in[14];
    float* out = (float*)d_out;

    char* ws = (char*)d_ws;
    _Float16* w1h  = (_Float16*)(ws);                         // 128 KB
    _Float16* w2h  = (_Float16*)(ws + 131072);                // 16 KB
    _Float16* ve1h = (_Float16*)(ws + 147456);                // 4 KB slot
    _Float16* de1h = (_Float16*)(ws + 151552);                // 4 KB slot
    _Float16* se1h = (_Float16*)(ws + 155648);                // 24 KB
    _Float16* ve2h = (_Float16*)(ws + 180224);                // 4 KB slot
    _Float16* de2h = (_Float16*)(ws + 184320);                // 4 KB slot
    _Float16* se2h = (_Float16*)(ws + 188416);                // 24 KB
    _Float16* y_c  = (_Float16*)(ws + 212992);                // 8 MB
    int* order1 = (int*)(ws + 212992 + 8388608);              // 1 MB
    int* dst2   = (int*)(ws + 212992 + 8388608 + 1048576);    // 512 KB
    int* cnt2   = (int*)(ws + 212992 + 8388608 + 1048576 + 524288); // 128 B

    k_pre<<<256, 256, 0, stream>>>(w1, w2, ve1, de1, se1, ve2, de2, se2,
                                   w1h, w2h, ve1h, de1h, se1h, ve2h, de2h, se2h);
    k_scan<<<dim3(BATCH, 2), 256, 0, stream>>>(value, order1, dst2, cnt2);
    k_conv2<<<1024, 256, 0, stream>>>(value, depth, pos, ve2h, de2h, se2h,
                                      w2h, b2, dst2, y_c);
    k_conv1<<<512, 256, 0, stream>>>(value, depth, pos, ve1h, de1h, se1h,
                                     w1h, b1, order1, cnt2, y_c, out);
}

// Round 6
// 45.206 us; speedup vs baseline: 4.1904x; 1.2459x over previous
//
#include <hip/hip_runtime.h>

// ---- problem constants (fixed by the reference) ----
#define BATCH   32
#define L1N     8192
#define L2N     32768
#define LTOT    40960
#define CD      32       // CONV_DEPTH
#define O1      256      // EMBED_DIM
#define L1P     1024     // L1N / 8
#define L2P     4096     // L2N / 8

typedef __attribute__((ext_vector_type(8))) _Float16 h16x8;
typedef __attribute__((ext_vector_type(4))) float f32x4;

// ---------------------------------------------------------------------------
// Fused pre-pass + scans.  grid.x = 320 blocks of 256:
//   blocks 0..31   : order1 scan (b = bid)
//   blocks 32..63  : dst2 scan + cnt2 (b = bid-32)
//   blocks 64..319 : weight/table conversion to fp16
// ---------------------------------------------------------------------------
__global__ __launch_bounds__(256) void k_prescan(
        const int* __restrict__ value,
        const float* __restrict__ w1, const float* __restrict__ w2,
        const float* __restrict__ ve1, const float* __restrict__ de1,
        const float* __restrict__ se1, const float* __restrict__ ve2,
        const float* __restrict__ de2, const float* __restrict__ se2,
        _Float16* __restrict__ w1h, _Float16* __restrict__ w2h,
        _Float16* __restrict__ ve1h, _Float16* __restrict__ de1h,
        _Float16* __restrict__ se1h, _Float16* __restrict__ ve2h,
        _Float16* __restrict__ de2h, _Float16* __restrict__ se2h,
        int* __restrict__ order1, int* __restrict__ dst2,
        int* __restrict__ cnt2) {
    int bid = blockIdx.x, tid = threadIdx.x;
    if (bid >= 64) {
        int i = (bid - 64) * 256 + tid;       // 65536 jobs
        if (i < 65536) {
            int o = i >> 8, k = i & 255, s = k >> 5, c = k & 31;
            w1h[i] = (_Float16)w1[o * 256 + c * 8 + s];
        }
        if (i < 8192) {
            int o = i >> 8, k = i & 255, s = k >> 5, c = k & 31;
            w2h[i] = (_Float16)w2[o * 256 + c * 8 + s];
        }
        if (i < 544) { ve1h[i] = (_Float16)ve1[i]; ve2h[i] = (_Float16)ve2[i]; }
        if (i < 224) { de1h[i] = (_Float16)de1[i]; de2h[i] = (_Float16)de2[i]; }
        if (i < 12288) { se1h[i] = (_Float16)se1[i]; se2h[i] = (_Float16)se2[i]; }
        return;
    }
    int lane = tid & 63, wid = tid >> 6;
    __shared__ int wsum[4];
    if (bid < 32) {
        int b = bid;
        const int4* v = (const int4*)(value + b * LTOT) + tid * 8;  // 32 ints
        int4 r[8];
        #pragma unroll
        for (int j = 0; j < 8; ++j) r[j] = v[j];
        int cnt = 0;
        #pragma unroll
        for (int j = 0; j < 8; ++j)
            cnt += (r[j].x == 2) + (r[j].y == 2) + (r[j].z == 2) + (r[j].w == 2);
        int sc = cnt;
        #pragma unroll
        for (int d = 1; d < 64; d <<= 1) {
            int t = __shfl_up(sc, d);
            if (lane >= d) sc += t;
        }
        if (lane == 63) wsum[wid] = sc;
        __syncthreads();
        int base = 0;
        for (int w = 0; w < 4; ++w) if (w < wid) base += wsum[w];
        int run = base + sc - cnt;             // exclusive prefix
        int4* o = (int4*)(order1 + b * L1N + tid * 32);
        #pragma unroll
        for (int j = 0; j < 8; ++j) {
            int vv[4] = {r[j].x, r[j].y, r[j].z, r[j].w};
            int ot[4];
            #pragma unroll
            for (int i = 0; i < 4; ++i) {
                bool m = (vv[i] == 2);
                int ord = run < (L2P - 1) ? run : (L2P - 1);
                ot[i] = m ? ord : -1;
                run += m;
            }
            o[j] = make_int4(ot[0], ot[1], ot[2], ot[3]);
        }
    } else {
        int b = bid - 32;
        const int* v2 = value + b * LTOT + L1N + tid * 16 * 8;
        int m[16]; int cnt = 0;
        #pragma unroll
        for (int i = 0; i < 16; ++i) { m[i] = (v2[i * 8] != 0); cnt += m[i]; }
        int sc = cnt;
        #pragma unroll
        for (int d = 1; d < 64; d <<= 1) {
            int t = __shfl_up(sc, d);
            if (lane >= d) sc += t;
        }
        if (lane == 63) wsum[wid] = sc;
        __syncthreads();
        int base = 0;
        for (int w = 0; w < 4; ++w) if (w < wid) base += wsum[w];
        int run = base + sc - cnt;
        int* o = dst2 + b * L2P + tid * 16;
        #pragma unroll
        for (int i = 0; i < 16; i += 4) {
            int ot[4];
            #pragma unroll
            for (int k2 = 0; k2 < 4; ++k2) { ot[k2] = m[i + k2] ? run : -1; run += m[i + k2]; }
            *(int4*)(o + i) = make_int4(ot[0], ot[1], ot[2], ot[3]);
        }
        if (tid == 255) cnt2[b] = base + sc;
    }
}

// ---------------------------------------------------------------------------
// conv2 (MFMA f16, software-pipelined): embed2 -> GEMM M=131072,K=256,N=32 ->
// bias -> compact scatter (fp16, 16B stores via LDS repack).
// Block: 64 M-rows, 256 thr (4 waves; each wave 16 rows x 32 N).
// All 8 jobs' indices preloaded; table gathers for kc+1 overlap MFMA of kc.
// ---------------------------------------------------------------------------
__global__ __launch_bounds__(256, 3) void k_conv2(
    const int* __restrict__ value, const int* __restrict__ depth,
    const int* __restrict__ pos,
    const _Float16* __restrict__ ve2h, const _Float16* __restrict__ de2h,
    const _Float16* __restrict__ se2h,
    const _Float16* __restrict__ w2h, const float* __restrict__ b2,
    const int* __restrict__ dst2, _Float16* __restrict__ y_c) {
    int tid = threadIdx.x, lane = tid & 63, wid = tid >> 6;
    int q = tid & 3, tg = tid >> 2;
    int g0 = blockIdx.x * 64, b = g0 >> 12, l2b = g0 & (L2P - 1);
    __shared__ _Float16 As[2][64 * 64];   // 8 KB x2
    __shared__ _Float16 Bs[32 * 256];     // 16 KB
    f32x4 acc[2] = {};
    int m0 = wid * 16;

    // ---- preload all 8 jobs' indices (j = kc*2 + r) ----
    int valv[8], depv[8], p0v[8], p1v[8], p2v[8];
    #pragma unroll
    for (int j = 0; j < 8; ++j) {
        int kc = j >> 1, r = j & 1;
        int t = r * 64 + tg, m = t >> 1, sh = t & 1;
        int tok = b * LTOT + L1N + (l2b + m) * 8 + kc * 2 + sh;
        valv[j] = value[tok];
        depv[j] = depth[tok];
        const int* pp = pos + (size_t)tok * 3;
        p0v[j] = pp[0]; p1v[j] = pp[1] + 128; p2v[j] = pp[2] + 256;
    }

    h16x8 row[2][5];
    #define PREF2(j, slot) { \
        row[slot][0] = *(const h16x8*)(ve2h + valv[j] * CD + q * 8); \
        row[slot][1] = *(const h16x8*)(de2h + depv[j] * CD + q * 8); \
        row[slot][2] = *(const h16x8*)(se2h + p0v[j] * CD + q * 8); \
        row[slot][3] = *(const h16x8*)(se2h + p1v[j] * CD + q * 8); \
        row[slot][4] = *(const h16x8*)(se2h + p2v[j] * CD + q * 8); }
    #define PACK2(j, slot, buf) { \
        int t = (j & 1) * 64 + tg, m = t >> 1, sh = t & 1; \
        h16x8 sum = (row[slot][0] + row[slot][1]) + \
                    (row[slot][2] + row[slot][3]) + row[slot][4]; \
        int c16 = sh * 4 + q; \
        *(h16x8*)&As[buf][m * 64 + ((c16 ^ (m & 7)) * 8)] = sum; }

    PREF2(0, 0); PREF2(1, 1);
    // stage all of B once
    #pragma unroll
    for (int it = 0; it < 4; ++it) {
        int idx = it * 256 + tid;
        int o = idx >> 5, c16 = idx & 31;
        h16x8 v = *(const h16x8*)(w2h + o * 256 + c16 * 8);
        *(h16x8*)&Bs[o * 256 + ((c16 ^ (o & 7)) * 8)] = v;
    }
    PACK2(0, 0, 0); PACK2(1, 1, 0);
    __syncthreads();

    #pragma unroll
    for (int kc = 0; kc < 4; ++kc) {
        int cur = kc & 1;
        if (kc < 3) { PREF2(2 * kc + 2, 0); PREF2(2 * kc + 3, 1); }
        // ---- MFMA from As[cur] ----
        #pragma unroll
        for (int ks = 0; ks < 2; ++ks) {
            int c16a = ks * 4 + (lane >> 4);
            int r0 = m0 + (lane & 15);
            h16x8 a0 = *(const h16x8*)&As[cur][r0 * 64 + ((c16a ^ (r0 & 7)) * 8)];
            int c16b = kc * 8 + ks * 4 + (lane >> 4);
            #pragma unroll
            for (int nt = 0; nt < 2; ++nt) {
                int n = nt * 16 + (lane & 15);
                h16x8 bv = *(const h16x8*)&Bs[n * 256 + ((c16b ^ (n & 7)) * 8)];
                acc[nt] = __builtin_amdgcn_mfma_f32_16x16x32_f16(a0, bv, acc[nt], 0, 0, 0);
            }
        }
        if (kc < 3) { PACK2(2 * kc + 2, 0, cur ^ 1); PACK2(2 * kc + 3, 1, cur ^ 1); }
        __syncthreads();
    }

    // ---- epilogue: bias -> LDS repack (stride 40) -> 16B compact scatter ----
    _Float16* sm = &As[0][0];                 // 64 x 40 fp16 = 5 KB
    #pragma unroll
    for (int nt = 0; nt < 2; ++nt) {
        int n = nt * 16 + (lane & 15);
        float bias = b2[n];
        #pragma unroll
        for (int r = 0; r < 4; ++r) {
            int ml = m0 + (lane >> 4) * 4 + r;
            sm[ml * 40 + n] = (_Float16)(acc[nt][r] + bias);
        }
    }
    __syncthreads();
    {
        int rowi = tg;                        // 0..63
        int d = dst2[b * L2P + l2b + rowi];
        h16x8 v = *(const h16x8*)&sm[rowi * 40 + q * 8];
        if (d >= 0)
            *(h16x8*)(y_c + ((size_t)(b * L2P + d)) * CD + q * 8) = v;
    }
    #undef PREF2
    #undef PACK2
}

// ---------------------------------------------------------------------------
// conv1 (MFMA f16, software-pipelined A and B): embed1 + substitution gather
// -> GEMM M=32768,K=256,N=256.  Block: 64M x 256N, 256 thr (4 waves of
// 32Mx128N).  val/ord preloaded for all 8 jobs; dep/pos + table gathers and
// the next B K-chunk (global->reg) overlap MFMA; reg->LDS after.
// ---------------------------------------------------------------------------
__global__ __launch_bounds__(256, 2) void k_conv1(
    const int* __restrict__ value, const int* __restrict__ depth,
    const int* __restrict__ pos,
    const _Float16* __restrict__ ve1h, const _Float16* __restrict__ de1h,
    const _Float16* __restrict__ se1h,
    const _Float16* __restrict__ w1h, const float* __restrict__ b1,
    const int* __restrict__ order1, const int* __restrict__ cnt2,
    const _Float16* __restrict__ y_c, float* __restrict__ out) {
    int tid = threadIdx.x, lane = tid & 63, wid = tid >> 6;
    int q = tid & 3, tg = tid >> 2;
    int g0 = blockIdx.x * 64, b = g0 >> 10, lb = g0 & (L1P - 1);
    __shared__ _Float16 As[2][64 * 64];    // 8 KB x2
    __shared__ _Float16 Bs[2][256 * 64];   // 32 KB x2
    f32x4 acc[2][8] = {};
    int m0 = (wid & 1) * 32, n0 = (wid >> 1) * 128;
    int c2 = cnt2[b];

    // ---- preload val/ord for all 8 jobs ----
    int valv[8], ordv[8];
    #pragma unroll
    for (int j = 0; j < 8; ++j) {
        int kc = j >> 1, r = j & 1;
        int t = r * 64 + tg, m = t >> 1, sh = t & 1;
        int tokl = (lb + m) * 8 + kc * 2 + sh;
        valv[j] = value[b * LTOT + tokl];
        ordv[j] = order1[b * L1N + tokl];
    }

    h16x8 row[2][5];
    h16x8 breg[8];
    #define PREF1(j, slot) { \
        int kc_ = j >> 1, r_ = j & 1; \
        int t_ = r_ * 64 + tg, m_ = t_ >> 1, sh_ = t_ & 1; \
        int tokl_ = (lb + m_) * 8 + kc_ * 2 + sh_; \
        int tok_ = b * LTOT + tokl_; \
        int vv = valv[j]; \
        bool sub = (vv == 2); \
        int o_ = ordv[j]; \
        bool valid = sub && (o_ < c2); \
        int dep = sub ? 0 : depth[tok_]; \
        const int* pp = pos + (size_t)tok_ * 3; \
        int p0 = sub ? 0 : pp[0]; \
        int p1 = sub ? 128 : (pp[1] + 128); \
        int p2 = sub ? 256 : (pp[2] + 256); \
        const _Float16* base0 = valid \
            ? (y_c + ((size_t)(b * L2P + o_)) * CD + q * 8) \
            : (ve1h + (sub ? 0 : vv * CD) + q * 8); \
        row[slot][0] = *(const h16x8*)base0; \
        row[slot][1] = *(const h16x8*)(de1h + dep * CD + q * 8); \
        row[slot][2] = *(const h16x8*)(se1h + p0 * CD + q * 8); \
        row[slot][3] = *(const h16x8*)(se1h + p1 * CD + q * 8); \
        row[slot][4] = *(const h16x8*)(se1h + p2 * CD + q * 8); }
    #define PACK1(j, slot, buf) { \
        int t_ = (j & 1) * 64 + tg, m_ = t_ >> 1, sh_ = t_ & 1; \
        h16x8 sum = (row[slot][0] + row[slot][1]) + \
                    (row[slot][2] + row[slot][3]) + row[slot][4]; \
        int c16 = sh_ * 4 + q; \
        *(h16x8*)&As[buf][m_ * 64 + ((c16 ^ (m_ & 7)) * 8)] = sum; }
    #define BLOAD(kc) { \
        _Pragma("unroll") \
        for (int it = 0; it < 8; ++it) { \
            int idx = it * 256 + tid; \
            int o = idx >> 3, c16 = idx & 7; \
            breg[it] = *(const h16x8*)(w1h + o * 256 + (kc) * 64 + c16 * 8); } }
    #define BSTORE(buf) { \
        _Pragma("unroll") \
        for (int it = 0; it < 8; ++it) { \
            int idx = it * 256 + tid; \
            int o = idx >> 3, c16 = idx & 7; \
            *(h16x8*)&Bs[buf][o * 64 + ((c16 ^ (o & 7)) * 8)] = breg[it]; } }

    BLOAD(0); PREF1(0, 0); PREF1(1, 1);
    BSTORE(0); PACK1(0, 0, 0); PACK1(1, 1, 0);
    __syncthreads();

    #pragma unroll
    for (int kc = 0; kc < 4; ++kc) {
        int cur = kc & 1;
        if (kc < 3) { BLOAD(kc + 1); PREF1(2 * kc + 2, 0); PREF1(2 * kc + 3, 1); }
        // ---- MFMA: 2 m-frags x 8 n-frags x 2 K-steps ----
        #pragma unroll
        for (int ks = 0; ks < 2; ++ks) {
            int c16 = ks * 4 + (lane >> 4);
            int r0 = m0 + (lane & 15), r1 = r0 + 16;
            h16x8 a0 = *(const h16x8*)&As[cur][r0 * 64 + ((c16 ^ (r0 & 7)) * 8)];
            h16x8 a1 = *(const h16x8*)&As[cur][r1 * 64 + ((c16 ^ (r1 & 7)) * 8)];
            #pragma unroll
            for (int nt = 0; nt < 8; ++nt) {
                int n = n0 + nt * 16 + (lane & 15);
                h16x8 bv = *(const h16x8*)&Bs[cur][n * 64 + ((c16 ^ (n & 7)) * 8)];
                acc[0][nt] = __builtin_amdgcn_mfma_f32_16x16x32_f16(a0, bv, acc[0][nt], 0, 0, 0);
                acc[1][nt] = __builtin_amdgcn_mfma_f32_16x16x32_f16(a1, bv, acc[1][nt], 0, 0, 0);
            }
        }
        if (kc < 3) {
            BSTORE(cur ^ 1);
            PACK1(2 * kc + 2, 0, cur ^ 1); PACK1(2 * kc + 3, 1, cur ^ 1);
        }
        __syncthreads();
    }

    // ---- epilogue: bias + fp32 store ----
    #pragma unroll
    for (int nt = 0; nt < 8; ++nt) {
        int n = n0 + nt * 16 + (lane & 15);
        float bias = b1[n];
        #pragma unroll
        for (int mt = 0; mt < 2; ++mt)
            #pragma unroll
            for (int r = 0; r < 4; ++r) {
                int g = g0 + m0 + mt * 16 + (lane >> 4) * 4 + r;
                out[(size_t)g * O1 + n] = acc[mt][nt][r] + bias;
            }
    }
    #undef PREF1
    #undef PACK1
    #undef BLOAD
    #undef BSTORE
}

// ---------------------------------------------------------------------------
extern "C" void kernel_launch(void* const* d_in, const int* in_sizes, int n_in,
                              void* d_out, int out_size, void* d_ws, size_t ws_size,
                              hipStream_t stream) {
    const int* value = (const int*)d_in[0];
    const int* depth = (const int*)d_in[1];
    const int* pos   = (const int*)d_in[2];
    const float* ve1 = (const float*)d_in[5];
    const float* de1 = (const float*)d_in[6];
    const float* se1 = (const float*)d_in[7];
    const float* ve2 = (const float*)d_in[8];
    const float* de2 = (const float*)d_in[9];
    const float* se2 = (const float*)d_in[10];
    const float* w1  = (const float*)d_in[11];
    const float* b1  = (const float*)d_in[12];
    const float* w2  = (const float*)d_in[13];
    const float* b2  = (const float*)d_in[14];
    float* out = (float*)d_out;

    char* ws = (char*)d_ws;
    _Float16* w1h  = (_Float16*)(ws);                         // 128 KB
    _Float16* w2h  = (_Float16*)(ws + 131072);                // 16 KB
    _Float16* ve1h = (_Float16*)(ws + 147456);                // 4 KB slot
    _Float16* de1h = (_Float16*)(ws + 151552);                // 4 KB slot
    _Float16* se1h = (_Float16*)(ws + 155648);                // 24 KB
    _Float16* ve2h = (_Float16*)(ws + 180224);                // 4 KB slot
    _Float16* de2h = (_Float16*)(ws + 184320);                // 4 KB slot
    _Float16* se2h = (_Float16*)(ws + 188416);                // 24 KB
    _Float16* y_c  = (_Float16*)(ws + 212992);                // 8 MB
    int* order1 = (int*)(ws + 212992 + 8388608);              // 1 MB
    int* dst2   = (int*)(ws + 212992 + 8388608 + 1048576);    // 512 KB
    int* cnt2   = (int*)(ws + 212992 + 8388608 + 1048576 + 524288); // 128 B

    k_prescan<<<320, 256, 0, stream>>>(value, w1, w2, ve1, de1, se1,
                                       ve2, de2, se2, w1h, w2h,
                                       ve1h, de1h, se1h, ve2h, de2h, se2h,
                                       order1, dst2, cnt2);
    k_conv2<<<2048, 256, 0, stream>>>(value, depth, pos, ve2h, de2h, se2h,
                                      w2h, b2, dst2, y_c);
    k_conv1<<<512, 256, 0, stream>>>(value, depth, pos, ve1h, de1h, se1h,
                                     w1h, b1, order1, cnt2, y_c, out);
}

// Round 7
// 43.939 us; speedup vs baseline: 4.3113x; 1.0288x over previous
//
#include <hip/hip_runtime.h>

// ---- problem constants (fixed by the reference) ----
#define BATCH   32
#define L1N     8192
#define L2N     32768
#define LTOT    40960
#define CD      32       // CONV_DEPTH
#define O1      256      // EMBED_DIM
#define L1P     1024     // L1N / 8
#define L2P     4096     // L2N / 8

typedef __attribute__((ext_vector_type(8))) _Float16 h16x8;
typedef __attribute__((ext_vector_type(4))) float f32x4;

// ---------------------------------------------------------------------------
// Fused pre-pass + scans.  grid.x = 320 blocks of 256:
//   blocks 0..31   : order1 scan (b = bid)
//   blocks 32..63  : dst2 scan + cnt2 (b = bid-32)
//   blocks 64..319 : weight conversion + combined vd tables + se tables
// vd[(val*7+dep)] = ve[val] + de[dep]  (119 rows x 32 ch, fp16)
// ---------------------------------------------------------------------------
__global__ __launch_bounds__(256) void k_prescan(
        const int* __restrict__ value,
        const float* __restrict__ w1, const float* __restrict__ w2,
        const float* __restrict__ ve1, const float* __restrict__ de1,
        const float* __restrict__ se1, const float* __restrict__ ve2,
        const float* __restrict__ de2, const float* __restrict__ se2,
        _Float16* __restrict__ w1h, _Float16* __restrict__ w2h,
        _Float16* __restrict__ vd1h, _Float16* __restrict__ vd2h,
        _Float16* __restrict__ se1h, _Float16* __restrict__ se2h,
        int* __restrict__ order1, int* __restrict__ dst2,
        int* __restrict__ cnt2) {
    int bid = blockIdx.x, tid = threadIdx.x;
    if (bid >= 64) {
        int i = (bid - 64) * 256 + tid;       // 65536 jobs
        if (i < 65536) {
            int o = i >> 8, k = i & 255, s = k >> 5, c = k & 31;
            w1h[i] = (_Float16)w1[o * 256 + c * 8 + s];
        }
        if (i < 8192) {
            int o = i >> 8, k = i & 255, s = k >> 5, c = k & 31;
            w2h[i] = (_Float16)w2[o * 256 + c * 8 + s];
        }
        if (i < 3808) {                        // 119 rows x 32
            int row = i >> 5, c = i & 31;
            int v = row / 7, d = row % 7;
            vd1h[i] = (_Float16)(ve1[v * 32 + c] + de1[d * 32 + c]);
            vd2h[i] = (_Float16)(ve2[v * 32 + c] + de2[d * 32 + c]);
        }
        if (i < 12288) { se1h[i] = (_Float16)se1[i]; se2h[i] = (_Float16)se2[i]; }
        return;
    }
    int lane = tid & 63, wid = tid >> 6;
    __shared__ int wsum[4];
    if (bid < 32) {
        int b = bid;
        const int4* v = (const int4*)(value + b * LTOT) + tid * 8;  // 32 ints
        int4 r[8];
        #pragma unroll
        for (int j = 0; j < 8; ++j) r[j] = v[j];
        int cnt = 0;
        #pragma unroll
        for (int j = 0; j < 8; ++j)
            cnt += (r[j].x == 2) + (r[j].y == 2) + (r[j].z == 2) + (r[j].w == 2);
        int sc = cnt;
        #pragma unroll
        for (int d = 1; d < 64; d <<= 1) {
            int t = __shfl_up(sc, d);
            if (lane >= d) sc += t;
        }
        if (lane == 63) wsum[wid] = sc;
        __syncthreads();
        int base = 0;
        for (int w = 0; w < 4; ++w) if (w < wid) base += wsum[w];
        int run = base + sc - cnt;             // exclusive prefix
        int4* o = (int4*)(order1 + b * L1N + tid * 32);
        #pragma unroll
        for (int j = 0; j < 8; ++j) {
            int vv[4] = {r[j].x, r[j].y, r[j].z, r[j].w};
            int ot[4];
            #pragma unroll
            for (int i = 0; i < 4; ++i) {
                bool m = (vv[i] == 2);
                int ord = run < (L2P - 1) ? run : (L2P - 1);
                ot[i] = m ? ord : -1;
                run += m;
            }
            o[j] = make_int4(ot[0], ot[1], ot[2], ot[3]);
        }
    } else {
        int b = bid - 32;
        const int* v2 = value + b * LTOT + L1N + tid * 16 * 8;
        int m[16]; int cnt = 0;
        #pragma unroll
        for (int i = 0; i < 16; ++i) { m[i] = (v2[i * 8] != 0); cnt += m[i]; }
        int sc = cnt;
        #pragma unroll
        for (int d = 1; d < 64; d <<= 1) {
            int t = __shfl_up(sc, d);
            if (lane >= d) sc += t;
        }
        if (lane == 63) wsum[wid] = sc;
        __syncthreads();
        int base = 0;
        for (int w = 0; w < 4; ++w) if (w < wid) base += wsum[w];
        int run = base + sc - cnt;
        int* o = dst2 + b * L2P + tid * 16;
        #pragma unroll
        for (int i = 0; i < 16; i += 4) {
            int ot[4];
            #pragma unroll
            for (int k2 = 0; k2 < 4; ++k2) { ot[k2] = m[i + k2] ? run : -1; run += m[i + k2]; }
            *(int4*)(o + i) = make_int4(ot[0], ot[1], ot[2], ot[3]);
        }
        if (tid == 255) cnt2[b] = base + sc;
    }
}

// ---------------------------------------------------------------------------
// conv2 (MFMA f16, pipelined): embed2 -> GEMM M=131072,K=256,N=32 -> bias ->
// compact scatter (fp16, 16B stores via LDS repack).
// Block: 128 M-rows, 512 thr (8 waves x 16 rows).  4 gathers/token (vd,se*3).
// ---------------------------------------------------------------------------
__global__ __launch_bounds__(512, 2) void k_conv2(
    const int* __restrict__ value, const int* __restrict__ depth,
    const int* __restrict__ pos,
    const _Float16* __restrict__ vd2h, const _Float16* __restrict__ se2h,
    const _Float16* __restrict__ w2h, const float* __restrict__ b2,
    const int* __restrict__ dst2, _Float16* __restrict__ y_c) {
    int tid = threadIdx.x, lane = tid & 63, wid = tid >> 6;
    int q = tid & 3, tg = tid >> 2;           // 128 groups x 16B
    int g0 = blockIdx.x * 128, b = g0 >> 12, l2b = g0 & (L2P - 1);
    __shared__ _Float16 As[2][128 * 64];  // 16 KB x2
    __shared__ _Float16 Bs[32 * 256];     // 16 KB
    f32x4 acc[2] = {};
    int m0 = wid * 16;

    // ---- preload all 8 jobs' indices (j = kc*2 + r) ----
    int ivv[8], p0v[8], p1v[8], p2v[8];
    #pragma unroll
    for (int j = 0; j < 8; ++j) {
        int kc = j >> 1, r = j & 1;
        int t = r * 128 + tg, m = t >> 1, sh = t & 1;
        int tok = b * LTOT + L1N + (l2b + m) * 8 + kc * 2 + sh;
        ivv[j] = (value[tok] * 7 + depth[tok]) * CD;
        const int* pp = pos + (size_t)tok * 3;
        p0v[j] = pp[0] * CD; p1v[j] = (pp[1] + 128) * CD; p2v[j] = (pp[2] + 256) * CD;
    }

    h16x8 row[2][4];
    #define PREF2(j, slot) { \
        row[slot][0] = *(const h16x8*)(vd2h + ivv[j] + q * 8); \
        row[slot][1] = *(const h16x8*)(se2h + p0v[j] + q * 8); \
        row[slot][2] = *(const h16x8*)(se2h + p1v[j] + q * 8); \
        row[slot][3] = *(const h16x8*)(se2h + p2v[j] + q * 8); }
    #define PACK2(j, slot, buf) { \
        int t = (j & 1) * 128 + tg, m = t >> 1, sh = t & 1; \
        h16x8 sum = (row[slot][0] + row[slot][1]) + \
                    (row[slot][2] + row[slot][3]); \
        int c16 = sh * 4 + q; \
        *(h16x8*)&As[buf][m * 64 + ((c16 ^ (m & 7)) * 8)] = sum; }

    PREF2(0, 0); PREF2(1, 1);
    // stage all of B once (1024 chunks, 2 iters)
    #pragma unroll
    for (int it = 0; it < 2; ++it) {
        int idx = it * 512 + tid;
        int o = idx >> 5, c16 = idx & 31;
        h16x8 v = *(const h16x8*)(w2h + o * 256 + c16 * 8);
        *(h16x8*)&Bs[o * 256 + ((c16 ^ (o & 7)) * 8)] = v;
    }
    PACK2(0, 0, 0); PACK2(1, 1, 0);
    __syncthreads();

    #pragma unroll
    for (int kc = 0; kc < 4; ++kc) {
        int cur = kc & 1;
        if (kc < 3) { PREF2(2 * kc + 2, 0); PREF2(2 * kc + 3, 1); }
        // ---- MFMA from As[cur] ----
        #pragma unroll
        for (int ks = 0; ks < 2; ++ks) {
            int c16a = ks * 4 + (lane >> 4);
            int r0 = m0 + (lane & 15);
            h16x8 a0 = *(const h16x8*)&As[cur][r0 * 64 + ((c16a ^ (r0 & 7)) * 8)];
            int c16b = kc * 8 + ks * 4 + (lane >> 4);
            #pragma unroll
            for (int nt = 0; nt < 2; ++nt) {
                int n = nt * 16 + (lane & 15);
                h16x8 bv = *(const h16x8*)&Bs[n * 256 + ((c16b ^ (n & 7)) * 8)];
                acc[nt] = __builtin_amdgcn_mfma_f32_16x16x32_f16(a0, bv, acc[nt], 0, 0, 0);
            }
        }
        if (kc < 3) { PACK2(2 * kc + 2, 0, cur ^ 1); PACK2(2 * kc + 3, 1, cur ^ 1); }
        __syncthreads();
    }

    // ---- epilogue: bias -> LDS repack (stride 40) -> 16B compact scatter ----
    _Float16* sm = &As[0][0];                 // 128 x 40 fp16 = 10 KB
    #pragma unroll
    for (int nt = 0; nt < 2; ++nt) {
        int n = nt * 16 + (lane & 15);
        float bias = b2[n];
        #pragma unroll
        for (int r = 0; r < 4; ++r) {
            int ml = m0 + (lane >> 4) * 4 + r;
            sm[ml * 40 + n] = (_Float16)(acc[nt][r] + bias);
        }
    }
    __syncthreads();
    {
        int rowi = tg;                        // 0..127
        int d = dst2[b * L2P + l2b + rowi];
        h16x8 v = *(const h16x8*)&sm[rowi * 40 + q * 8];
        if (d >= 0)
            *(h16x8*)(y_c + ((size_t)(b * L2P + d)) * CD + q * 8) = v;
    }
    #undef PREF2
    #undef PACK2
}

// ---------------------------------------------------------------------------
// conv1 (MFMA f16, pipelined A and B): embed1 + substitution gather ->
// GEMM M=32768,K=256,N=256.  Block: 64M x 256N, 256 thr (4 waves 32Mx128N).
// Sub tokens (group-uniform): 1 y_c gather only; non-sub: vd + se*3 (4).
// ---------------------------------------------------------------------------
__global__ __launch_bounds__(256, 2) void k_conv1(
    const int* __restrict__ value, const int* __restrict__ depth,
    const int* __restrict__ pos,
    const _Float16* __restrict__ vd1h, const _Float16* __restrict__ se1h,
    const _Float16* __restrict__ w1h, const float* __restrict__ b1,
    const int* __restrict__ order1, const int* __restrict__ cnt2,
    const _Float16* __restrict__ y_c, float* __restrict__ out) {
    int tid = threadIdx.x, lane = tid & 63, wid = tid >> 6;
    int q = tid & 3, tg = tid >> 2;
    int g0 = blockIdx.x * 64, b = g0 >> 10, lb = g0 & (L1P - 1);
    __shared__ _Float16 As[2][64 * 64];    // 8 KB x2
    __shared__ _Float16 Bs[2][256 * 64];   // 32 KB x2
    f32x4 acc[2][8] = {};
    int m0 = (wid & 1) * 32, n0 = (wid >> 1) * 128;
    int c2 = cnt2[b];

    // ---- preload val/ord for all 8 jobs ----
    int valv[8], ordv[8];
    #pragma unroll
    for (int j = 0; j < 8; ++j) {
        int kc = j >> 1, r = j & 1;
        int t = r * 64 + tg, m = t >> 1, sh = t & 1;
        int tokl = (lb + m) * 8 + kc * 2 + sh;
        valv[j] = value[b * LTOT + tokl];
        ordv[j] = order1[b * L1N + tokl];
    }

    h16x8 row[2][4];
    h16x8 breg[8];
    #define PREF1(j, slot) { \
        int kc_ = j >> 1, r_ = j & 1; \
        int t_ = r_ * 64 + tg, m_ = t_ >> 1, sh_ = t_ & 1; \
        int tokl_ = (lb + m_) * 8 + kc_ * 2 + sh_; \
        int vv = valv[j]; \
        h16x8 z = {}; \
        row[slot][1] = z; row[slot][2] = z; row[slot][3] = z; \
        if (vv == 2) { \
            int o_ = ordv[j]; \
            row[slot][0] = (o_ < c2) \
                ? *(const h16x8*)(y_c + ((size_t)(b * L2P + o_)) * CD + q * 8) : z; \
        } else { \
            int tok_ = b * LTOT + tokl_; \
            int dep = depth[tok_]; \
            const int* pp = pos + (size_t)tok_ * 3; \
            row[slot][0] = *(const h16x8*)(vd1h + (vv * 7 + dep) * CD + q * 8); \
            row[slot][1] = *(const h16x8*)(se1h + pp[0] * CD + q * 8); \
            row[slot][2] = *(const h16x8*)(se1h + (pp[1] + 128) * CD + q * 8); \
            row[slot][3] = *(const h16x8*)(se1h + (pp[2] + 256) * CD + q * 8); \
        } }
    #define PACK1(j, slot, buf) { \
        int t_ = (j & 1) * 64 + tg, m_ = t_ >> 1, sh_ = t_ & 1; \
        h16x8 sum = (row[slot][0] + row[slot][1]) + \
                    (row[slot][2] + row[slot][3]); \
        int c16 = sh_ * 4 + q; \
        *(h16x8*)&As[buf][m_ * 64 + ((c16 ^ (m_ & 7)) * 8)] = sum; }
    #define BLOAD(kc) { \
        _Pragma("unroll") \
        for (int it = 0; it < 8; ++it) { \
            int idx = it * 256 + tid; \
            int o = idx >> 3, c16 = idx & 7; \
            breg[it] = *(const h16x8*)(w1h + o * 256 + (kc) * 64 + c16 * 8); } }
    #define BSTORE(buf) { \
        _Pragma("unroll") \
        for (int it = 0; it < 8; ++it) { \
            int idx = it * 256 + tid; \
            int o = idx >> 3, c16 = idx & 7; \
            *(h16x8*)&Bs[buf][o * 64 + ((c16 ^ (o & 7)) * 8)] = breg[it]; } }

    BLOAD(0); PREF1(0, 0); PREF1(1, 1);
    BSTORE(0); PACK1(0, 0, 0); PACK1(1, 1, 0);
    __syncthreads();

    #pragma unroll
    for (int kc = 0; kc < 4; ++kc) {
        int cur = kc & 1;
        if (kc < 3) { BLOAD(kc + 1); PREF1(2 * kc + 2, 0); PREF1(2 * kc + 3, 1); }
        // ---- MFMA: 2 m-frags x 8 n-frags x 2 K-steps ----
        #pragma unroll
        for (int ks = 0; ks < 2; ++ks) {
            int c16 = ks * 4 + (lane >> 4);
            int r0 = m0 + (lane & 15), r1 = r0 + 16;
            h16x8 a0 = *(const h16x8*)&As[cur][r0 * 64 + ((c16 ^ (r0 & 7)) * 8)];
            h16x8 a1 = *(const h16x8*)&As[cur][r1 * 64 + ((c16 ^ (r1 & 7)) * 8)];
            #pragma unroll
            for (int nt = 0; nt < 8; ++nt) {
                int n = n0 + nt * 16 + (lane & 15);
                h16x8 bv = *(const h16x8*)&Bs[cur][n * 64 + ((c16 ^ (n & 7)) * 8)];
                acc[0][nt] = __builtin_amdgcn_mfma_f32_16x16x32_f16(a0, bv, acc[0][nt], 0, 0, 0);
                acc[1][nt] = __builtin_amdgcn_mfma_f32_16x16x32_f16(a1, bv, acc[1][nt], 0, 0, 0);
            }
        }
        if (kc < 3) {
            BSTORE(cur ^ 1);
            PACK1(2 * kc + 2, 0, cur ^ 1); PACK1(2 * kc + 3, 1, cur ^ 1);
        }
        __syncthreads();
    }

    // ---- epilogue: bias + fp32 store ----
    #pragma unroll
    for (int nt = 0; nt < 8; ++nt) {
        int n = n0 + nt * 16 + (lane & 15);
        float bias = b1[n];
        #pragma unroll
        for (int mt = 0; mt < 2; ++mt)
            #pragma unroll
            for (int r = 0; r < 4; ++r) {
                int g = g0 + m0 + mt * 16 + (lane >> 4) * 4 + r;
                out[(size_t)g * O1 + n] = acc[mt][nt][r] + bias;
            }
    }
    #undef PREF1
    #undef PACK1
    #undef BLOAD
    #undef BSTORE
}

// ---------------------------------------------------------------------------
extern "C" void kernel_launch(void* const* d_in, const int* in_sizes, int n_in,
                              void* d_out, int out_size, void* d_ws, size_t ws_size,
                              hipStream_t stream) {
    const int* value = (const int*)d_in[0];
    const int* depth = (const int*)d_in[1];
    const int* pos   = (const int*)d_in[2];
    const float* ve1 = (const float*)d_in[5];
    const float* de1 = (const float*)d_in[6];
    const float* se1 = (const float*)d_in[7];
    const float* ve2 = (const float*)d_in[8];
    const float* de2 = (const float*)d_in[9];
    const float* se2 = (const float*)d_in[10];
    const float* w1  = (const float*)d_in[11];
    const float* b1  = (const float*)d_in[12];
    const float* w2  = (const float*)d_in[13];
    const float* b2  = (const float*)d_in[14];
    float* out = (float*)d_out;

    char* ws = (char*)d_ws;
    _Float16* w1h  = (_Float16*)(ws);                         // 128 KB
    _Float16* w2h  = (_Float16*)(ws + 131072);                // 16 KB
    _Float16* vd1h = (_Float16*)(ws + 147456);                // 8 KB slot
    _Float16* vd2h = (_Float16*)(ws + 155648);                // 8 KB slot
    _Float16* se1h = (_Float16*)(ws + 163840);                // 24 KB
    _Float16* se2h = (_Float16*)(ws + 188416);                // 24 KB
    _Float16* y_c  = (_Float16*)(ws + 212992);                // 8 MB
    int* order1 = (int*)(ws + 212992 + 8388608);              // 1 MB
    int* dst2   = (int*)(ws + 212992 + 8388608 + 1048576);    // 512 KB
    int* cnt2   = (int*)(ws + 212992 + 8388608 + 1048576 + 524288); // 128 B

    k_prescan<<<320, 256, 0, stream>>>(value, w1, w2, ve1, de1, se1,
                                       ve2, de2, se2, w1h, w2h,
                                       vd1h, vd2h, se1h, se2h,
                                       order1, dst2, cnt2);
    k_conv2<<<1024, 512, 0, stream>>>(value, depth, pos, vd2h, se2h,
                                      w2h, b2, dst2, y_c);
    k_conv1<<<512, 256, 0, stream>>>(value, depth, pos, vd1h, se1h,
                                     w1h, b1, order1, cnt2, y_c, out);
}

// Round 8
// 43.427 us; speedup vs baseline: 4.3621x; 1.0118x over previous
//
#include <hip/hip_runtime.h>

// ---- problem constants (fixed by the reference) ----
#define BATCH   32
#define L1N     8192
#define L2N     32768
#define LTOT    40960
#define CD      32       // CONV_DEPTH
#define O1      256      // EMBED_DIM
#define L1P     1024     // L1N / 8
#define L2P     4096     // L2N / 8

typedef __attribute__((ext_vector_type(8))) _Float16 h16x8;
typedef __attribute__((ext_vector_type(4))) float f32x4;

// ---------------------------------------------------------------------------
// Fused pre-pass + scans.  grid.x = 320 blocks of 256:
//   blocks 0..31   : order1 scan (b = bid)
//   blocks 32..63  : dst2 scan + cnt2 (b = bid-32)
//   blocks 64..319 : weight conversion + combined vd tables + se tables
// vd[(val*7+dep)] = ve[val] + de[dep]  (119 rows x 32 ch, fp16)
// ---------------------------------------------------------------------------
__global__ __launch_bounds__(256) void k_prescan(
        const int* __restrict__ value,
        const float* __restrict__ w1, const float* __restrict__ w2,
        const float* __restrict__ ve1, const float* __restrict__ de1,
        const float* __restrict__ se1, const float* __restrict__ ve2,
        const float* __restrict__ de2, const float* __restrict__ se2,
        _Float16* __restrict__ w1h, _Float16* __restrict__ w2h,
        _Float16* __restrict__ vd1h, _Float16* __restrict__ vd2h,
        _Float16* __restrict__ se1h, _Float16* __restrict__ se2h,
        int* __restrict__ order1, int* __restrict__ dst2,
        int* __restrict__ cnt2) {
    int bid = blockIdx.x, tid = threadIdx.x;
    if (bid >= 64) {
        int i = (bid - 64) * 256 + tid;       // 65536 jobs
        if (i < 65536) {
            int o = i >> 8, k = i & 255, s = k >> 5, c = k & 31;
            w1h[i] = (_Float16)w1[o * 256 + c * 8 + s];
        }
        if (i < 8192) {
            int o = i >> 8, k = i & 255, s = k >> 5, c = k & 31;
            w2h[i] = (_Float16)w2[o * 256 + c * 8 + s];
        }
        if (i < 3808) {                        // 119 rows x 32
            int row = i >> 5, c = i & 31;
            int v = row / 7, d = row % 7;
            vd1h[i] = (_Float16)(ve1[v * 32 + c] + de1[d * 32 + c]);
            vd2h[i] = (_Float16)(ve2[v * 32 + c] + de2[d * 32 + c]);
        }
        if (i < 12288) { se1h[i] = (_Float16)se1[i]; se2h[i] = (_Float16)se2[i]; }
        return;
    }
    int lane = tid & 63, wid = tid >> 6;
    __shared__ int wsum[4];
    if (bid < 32) {
        int b = bid;
        const int4* v = (const int4*)(value + b * LTOT) + tid * 8;  // 32 ints
        int4 r[8];
        #pragma unroll
        for (int j = 0; j < 8; ++j) r[j] = v[j];
        int cnt = 0;
        #pragma unroll
        for (int j = 0; j < 8; ++j)
            cnt += (r[j].x == 2) + (r[j].y == 2) + (r[j].z == 2) + (r[j].w == 2);
        int sc = cnt;
        #pragma unroll
        for (int d = 1; d < 64; d <<= 1) {
            int t = __shfl_up(sc, d);
            if (lane >= d) sc += t;
        }
        if (lane == 63) wsum[wid] = sc;
        __syncthreads();
        int base = 0;
        for (int w = 0; w < 4; ++w) if (w < wid) base += wsum[w];
        int run = base + sc - cnt;             // exclusive prefix
        int4* o = (int4*)(order1 + b * L1N + tid * 32);
        #pragma unroll
        for (int j = 0; j < 8; ++j) {
            int vv[4] = {r[j].x, r[j].y, r[j].z, r[j].w};
            int ot[4];
            #pragma unroll
            for (int i = 0; i < 4; ++i) {
                bool m = (vv[i] == 2);
                int ord = run < (L2P - 1) ? run : (L2P - 1);
                ot[i] = m ? ord : -1;
                run += m;
            }
            o[j] = make_int4(ot[0], ot[1], ot[2], ot[3]);
        }
    } else {
        int b = bid - 32;
        const int* v2 = value + b * LTOT + L1N + tid * 16 * 8;
        int m[16]; int cnt = 0;
        #pragma unroll
        for (int i = 0; i < 16; ++i) { m[i] = (v2[i * 8] != 0); cnt += m[i]; }
        int sc = cnt;
        #pragma unroll
        for (int d = 1; d < 64; d <<= 1) {
            int t = __shfl_up(sc, d);
            if (lane >= d) sc += t;
        }
        if (lane == 63) wsum[wid] = sc;
        __syncthreads();
        int base = 0;
        for (int w = 0; w < 4; ++w) if (w < wid) base += wsum[w];
        int run = base + sc - cnt;
        int* o = dst2 + b * L2P + tid * 16;
        #pragma unroll
        for (int i = 0; i < 16; i += 4) {
            int ot[4];
            #pragma unroll
            for (int k2 = 0; k2 < 4; ++k2) { ot[k2] = m[i + k2] ? run : -1; run += m[i + k2]; }
            *(int4*)(o + i) = make_int4(ot[0], ot[1], ot[2], ot[3]);
        }
        if (tid == 255) cnt2[b] = base + sc;
    }
}

// ---------------------------------------------------------------------------
// conv2 (MFMA f16, pipelined): embed2 -> GEMM M=131072,K=256,N=32 -> bias ->
// compact scatter (fp16, 16B stores via LDS repack).
// Block: 128 M-rows, 512 thr (8 waves x 16 rows).
// Index loads COALESCED via LDS staging (value/depth/pos int4 streams).
// ---------------------------------------------------------------------------
__global__ __launch_bounds__(512, 2) void k_conv2(
    const int* __restrict__ value, const int* __restrict__ depth,
    const int* __restrict__ pos,
    const _Float16* __restrict__ vd2h, const _Float16* __restrict__ se2h,
    const _Float16* __restrict__ w2h, const float* __restrict__ b2,
    const int* __restrict__ dst2, _Float16* __restrict__ y_c) {
    int tid = threadIdx.x, lane = tid & 63, wid = tid >> 6;
    int q = tid & 3, tg = tid >> 2;           // 128 groups x 16B
    int g0 = blockIdx.x * 128, b = g0 >> 12, l2b = g0 & (L2P - 1);
    __shared__ _Float16 As[2][128 * 64];  // 16 KB x2
    __shared__ _Float16 Bs[32 * 256];     // 16 KB
    f32x4 acc[2] = {};
    int m0 = wid * 16;

    // ---- coalesced index staging into the As region (20 KB scratch) ----
    int* sval = (int*)&As[0][0];          // 1024 ints
    int* sdep = sval + 1024;              // 1024 ints
    int* spos = sdep + 1024;              // 3072 ints
    {
        int tok0 = b * LTOT + L1N + l2b * 8;
        if (tid < 256) ((int4*)sval)[tid] = ((const int4*)(value + tok0))[tid];
        else           ((int4*)sdep)[tid - 256] = ((const int4*)(depth + tok0))[tid - 256];
        const int4* psrc = (const int4*)(pos + (size_t)tok0 * 3);
        ((int4*)spos)[tid] = psrc[tid];                        // 0..511
        if (tid < 256) ((int4*)spos)[512 + tid] = psrc[512 + tid];  // 512..767
    }
    __syncthreads();
    int ivv[8], p0v[8], p1v[8], p2v[8];
    #pragma unroll
    for (int j = 0; j < 8; ++j) {
        int t = (j & 1) * 128 + tg;
        int tl = (t >> 1) * 8 + (j >> 1) * 2 + (t & 1);   // token in block
        ivv[j] = (sval[tl] * 7 + sdep[tl]) * CD;
        p0v[j] = spos[tl * 3] * CD;
        p1v[j] = (spos[tl * 3 + 1] + 128) * CD;
        p2v[j] = (spos[tl * 3 + 2] + 256) * CD;
    }
    __syncthreads();

    h16x8 row[2][4];
    #define PREF2(j, slot) { \
        row[slot][0] = *(const h16x8*)(vd2h + ivv[j] + q * 8); \
        row[slot][1] = *(const h16x8*)(se2h + p0v[j] + q * 8); \
        row[slot][2] = *(const h16x8*)(se2h + p1v[j] + q * 8); \
        row[slot][3] = *(const h16x8*)(se2h + p2v[j] + q * 8); }
    #define PACK2(j, slot, buf) { \
        int t = (j & 1) * 128 + tg, m = t >> 1, sh = t & 1; \
        h16x8 sum = (row[slot][0] + row[slot][1]) + \
                    (row[slot][2] + row[slot][3]); \
        int c16 = sh * 4 + q; \
        *(h16x8*)&As[buf][m * 64 + ((c16 ^ (m & 7)) * 8)] = sum; }

    PREF2(0, 0); PREF2(1, 1);
    // stage all of B once (1024 chunks, 2 iters)
    #pragma unroll
    for (int it = 0; it < 2; ++it) {
        int idx = it * 512 + tid;
        int o = idx >> 5, c16 = idx & 31;
        h16x8 v = *(const h16x8*)(w2h + o * 256 + c16 * 8);
        *(h16x8*)&Bs[o * 256 + ((c16 ^ (o & 7)) * 8)] = v;
    }
    PACK2(0, 0, 0); PACK2(1, 1, 0);
    __syncthreads();

    #pragma unroll
    for (int kc = 0; kc < 4; ++kc) {
        int cur = kc & 1;
        if (kc < 3) { PREF2(2 * kc + 2, 0); PREF2(2 * kc + 3, 1); }
        // ---- MFMA from As[cur] ----
        #pragma unroll
        for (int ks = 0; ks < 2; ++ks) {
            int c16a = ks * 4 + (lane >> 4);
            int r0 = m0 + (lane & 15);
            h16x8 a0 = *(const h16x8*)&As[cur][r0 * 64 + ((c16a ^ (r0 & 7)) * 8)];
            int c16b = kc * 8 + ks * 4 + (lane >> 4);
            #pragma unroll
            for (int nt = 0; nt < 2; ++nt) {
                int n = nt * 16 + (lane & 15);
                h16x8 bv = *(const h16x8*)&Bs[n * 256 + ((c16b ^ (n & 7)) * 8)];
                acc[nt] = __builtin_amdgcn_mfma_f32_16x16x32_f16(a0, bv, acc[nt], 0, 0, 0);
            }
        }
        if (kc < 3) { PACK2(2 * kc + 2, 0, cur ^ 1); PACK2(2 * kc + 3, 1, cur ^ 1); }
        __syncthreads();
    }

    // ---- epilogue: bias -> LDS repack (stride 40) -> 16B compact scatter ----
    _Float16* sm = &As[0][0];                 // 128 x 40 fp16 = 10 KB
    #pragma unroll
    for (int nt = 0; nt < 2; ++nt) {
        int n = nt * 16 + (lane & 15);
        float bias = b2[n];
        #pragma unroll
        for (int r = 0; r < 4; ++r) {
            int ml = m0 + (lane >> 4) * 4 + r;
            sm[ml * 40 + n] = (_Float16)(acc[nt][r] + bias);
        }
    }
    __syncthreads();
    {
        int rowi = tg;                        // 0..127
        int d = dst2[b * L2P + l2b + rowi];
        h16x8 v = *(const h16x8*)&sm[rowi * 40 + q * 8];
        if (d >= 0)
            *(h16x8*)(y_c + ((size_t)(b * L2P + d)) * CD + q * 8) = v;
    }
    #undef PREF2
    #undef PACK2
}

// ---------------------------------------------------------------------------
// conv1 (MFMA f16, pipelined A and B): embed1 + substitution gather ->
// GEMM M=32768,K=256,N=256.  Block: 64M x 256N, 256 thr (4 waves 32Mx128N).
// Index loads COALESCED via LDS staging; sub tokens encoded as ~ord
// (all-zero table rows make the invalid-sub path collapse to zeros).
// ---------------------------------------------------------------------------
__global__ __launch_bounds__(256, 2) void k_conv1(
    const int* __restrict__ value, const int* __restrict__ depth,
    const int* __restrict__ pos,
    const _Float16* __restrict__ vd1h, const _Float16* __restrict__ se1h,
    const _Float16* __restrict__ w1h, const float* __restrict__ b1,
    const int* __restrict__ order1, const int* __restrict__ cnt2,
    const _Float16* __restrict__ y_c, float* __restrict__ out) {
    int tid = threadIdx.x, lane = tid & 63, wid = tid >> 6;
    int q = tid & 3, tg = tid >> 2;
    int g0 = blockIdx.x * 64, b = g0 >> 10, lb = g0 & (L1P - 1);
    __shared__ _Float16 As[2][64 * 64];    // 8 KB x2
    __shared__ _Float16 Bs[2][256 * 64];   // 32 KB x2
    f32x4 acc[2][8] = {};
    int m0 = (wid & 1) * 32, n0 = (wid >> 1) * 128;
    int c2 = cnt2[b];

    // ---- coalesced index staging into the As region (12 KB scratch) ----
    int* sval = (int*)&As[0][0];          // 512
    int* sord = sval + 512;               // 512
    int* sdep = sord + 512;               // 512
    int* spos = sdep + 512;               // 1536
    {
        int tok0 = b * LTOT + lb * 8;
        int o0 = b * L1N + lb * 8;
        const int4* vsrc = (const int4*)(value + tok0);
        const int4* dsrc = (const int4*)(depth + tok0);
        const int4* osrc = (const int4*)(order1 + o0);
        const int4* psrc = (const int4*)(pos + (size_t)tok0 * 3);
        if (tid < 128) { ((int4*)sval)[tid] = vsrc[tid]; ((int4*)sdep)[tid] = dsrc[tid]; }
        else { int o = tid - 128; ((int4*)sord)[o] = osrc[o]; ((int4*)spos)[o] = psrc[o]; }
        ((int4*)spos)[128 + tid] = psrc[128 + tid];    // 128..383
    }
    __syncthreads();
    int xv[8], p0v[8], p1v[8], p2v[8];
    #pragma unroll
    for (int j = 0; j < 8; ++j) {
        int t = (j & 1) * 64 + tg;
        int tl = (t >> 1) * 8 + (j >> 1) * 2 + (t & 1);
        int vv = sval[tl];
        if (vv == 2) {
            xv[j] = ~sord[tl];
            p0v[j] = 0; p1v[j] = 0; p2v[j] = 0;
        } else {
            xv[j] = (vv * 7 + sdep[tl]) * CD;
            p0v[j] = spos[tl * 3] * CD;
            p1v[j] = (spos[tl * 3 + 1] + 128) * CD;
            p2v[j] = (spos[tl * 3 + 2] + 256) * CD;
        }
    }
    __syncthreads();

    h16x8 row[2][4];
    h16x8 breg[8];
    #define PREF1(j, slot) { \
        int x_ = xv[j]; \
        h16x8 z = {}; \
        if (x_ < 0) { \
            int o_ = ~x_; \
            row[slot][0] = (o_ < c2) \
                ? *(const h16x8*)(y_c + ((size_t)(b * L2P + o_)) * CD + q * 8) : z; \
            row[slot][1] = z; row[slot][2] = z; row[slot][3] = z; \
        } else { \
            row[slot][0] = *(const h16x8*)(vd1h + x_ + q * 8); \
            row[slot][1] = *(const h16x8*)(se1h + p0v[j] + q * 8); \
            row[slot][2] = *(const h16x8*)(se1h + p1v[j] + q * 8); \
            row[slot][3] = *(const h16x8*)(se1h + p2v[j] + q * 8); \
        } }
    #define PACK1(j, slot, buf) { \
        int t_ = (j & 1) * 64 + tg, m_ = t_ >> 1, sh_ = t_ & 1; \
        h16x8 sum = (row[slot][0] + row[slot][1]) + \
                    (row[slot][2] + row[slot][3]); \
        int c16 = sh_ * 4 + q; \
        *(h16x8*)&As[buf][m_ * 64 + ((c16 ^ (m_ & 7)) * 8)] = sum; }
    #define BLOAD(kc) { \
        _Pragma("unroll") \
        for (int it = 0; it < 8; ++it) { \
            int idx = it * 256 + tid; \
            int o = idx >> 3, c16 = idx & 7; \
            breg[it] = *(const h16x8*)(w1h + o * 256 + (kc) * 64 + c16 * 8); } }
    #define BSTORE(buf) { \
        _Pragma("unroll") \
        for (int it = 0; it < 8; ++it) { \
            int idx = it * 256 + tid; \
            int o = idx >> 3, c16 = idx & 7; \
            *(h16x8*)&Bs[buf][o * 64 + ((c16 ^ (o & 7)) * 8)] = breg[it]; } }

    BLOAD(0); PREF1(0, 0); PREF1(1, 1);
    BSTORE(0); PACK1(0, 0, 0); PACK1(1, 1, 0);
    __syncthreads();

    #pragma unroll
    for (int kc = 0; kc < 4; ++kc) {
        int cur = kc & 1;
        if (kc < 3) { BLOAD(kc + 1); PREF1(2 * kc + 2, 0); PREF1(2 * kc + 3, 1); }
        // ---- MFMA: 2 m-frags x 8 n-frags x 2 K-steps ----
        #pragma unroll
        for (int ks = 0; ks < 2; ++ks) {
            int c16 = ks * 4 + (lane >> 4);
            int r0 = m0 + (lane & 15), r1 = r0 + 16;
            h16x8 a0 = *(const h16x8*)&As[cur][r0 * 64 + ((c16 ^ (r0 & 7)) * 8)];
            h16x8 a1 = *(const h16x8*)&As[cur][r1 * 64 + ((c16 ^ (r1 & 7)) * 8)];
            #pragma unroll
            for (int nt = 0; nt < 8; ++nt) {
                int n = n0 + nt * 16 + (lane & 15);
                h16x8 bv = *(const h16x8*)&Bs[cur][n * 64 + ((c16 ^ (n & 7)) * 8)];
                acc[0][nt] = __builtin_amdgcn_mfma_f32_16x16x32_f16(a0, bv, acc[0][nt], 0, 0, 0);
                acc[1][nt] = __builtin_amdgcn_mfma_f32_16x16x32_f16(a1, bv, acc[1][nt], 0, 0, 0);
            }
        }
        if (kc < 3) {
            BSTORE(cur ^ 1);
            PACK1(2 * kc + 2, 0, cur ^ 1); PACK1(2 * kc + 3, 1, cur ^ 1);
        }
        __syncthreads();
    }

    // ---- epilogue: bias + fp32 store ----
    #pragma unroll
    for (int nt = 0; nt < 8; ++nt) {
        int n = n0 + nt * 16 + (lane & 15);
        float bias = b1[n];
        #pragma unroll
        for (int mt = 0; mt < 2; ++mt)
            #pragma unroll
            for (int r = 0; r < 4; ++r) {
                int g = g0 + m0 + mt * 16 + (lane >> 4) * 4 + r;
                out[(size_t)g * O1 + n] = acc[mt][nt][r] + bias;
            }
    }
    #undef PREF1
    #undef PACK1
    #undef BLOAD
    #undef BSTORE
}

// ---------------------------------------------------------------------------
extern "C" void kernel_launch(void* const* d_in, const int* in_sizes, int n_in,
                              void* d_out, int out_size, void* d_ws, size_t ws_size,
                              hipStream_t stream) {
    const int* value = (const int*)d_in[0];
    const int* depth = (const int*)d_in[1];
    const int* pos   = (const int*)d_in[2];
    const float* ve1 = (const float*)d_in[5];
    const float* de1 = (const float*)d_in[6];
    const float* se1 = (const float*)d_in[7];
    const float* ve2 = (const float*)d_in[8];
    const float* de2 = (const float*)d_in[9];
    const float* se2 = (const float*)d_in[10];
    const float* w1  = (const float*)d_in[11];
    const float* b1  = (const float*)d_in[12];
    const float* w2  = (const float*)d_in[13];
    const float* b2  = (const float*)d_in[14];
    float* out = (float*)d_out;

    char* ws = (char*)d_ws;
    _Float16* w1h  = (_Float16*)(ws);                         // 128 KB
    _Float16* w2h  = (_Float16*)(ws + 131072);                // 16 KB
    _Float16* vd1h = (_Float16*)(ws + 147456);                // 8 KB slot
    _Float16* vd2h = (_Float16*)(ws + 155648);                // 8 KB slot
    _Float16* se1h = (_Float16*)(ws + 163840);                // 24 KB
    _Float16* se2h = (_Float16*)(ws + 188416);                // 24 KB
    _Float16* y_c  = (_Float16*)(ws + 212992);                // 8 MB
    int* order1 = (int*)(ws + 212992 + 8388608);              // 1 MB
    int* dst2   = (int*)(ws + 212992 + 8388608 + 1048576);    // 512 KB
    int* cnt2   = (int*)(ws + 212992 + 8388608 + 1048576 + 524288); // 128 B

    k_prescan<<<320, 256, 0, stream>>>(value, w1, w2, ve1, de1, se1,
                                       ve2, de2, se2, w1h, w2h,
                                       vd1h, vd2h, se1h, se2h,
                                       order1, dst2, cnt2);
    k_conv2<<<1024, 512, 0, stream>>>(value, depth, pos, vd2h, se2h,
                                      w2h, b2, dst2, y_c);
    k_conv1<<<512, 256, 0, stream>>>(value, depth, pos, vd1h, se1h,
                                     w1h, b1, order1, cnt2, y_c, out);
}